// Round 15
// baseline (160.899 us; speedup 1.0000x reference)
//
#include <hip/hip_runtime.h>
#include <hip/hip_bf16.h>

#define HW    5184
#define WIDTH 72
#define CIN   512
#define KC    256
#define VC    256
#define NS    110
#define NSP   112   // padded s for QK^T (7*16)
#define SPV   128   // padded s for PV k-dim (4*32)
#define BATCH 8

typedef unsigned short u16;
typedef unsigned int   u32;
typedef __attribute__((ext_vector_type(8))) short bf16x8;   // 8 bf16 = 4 VGPRs
typedef __attribute__((ext_vector_type(4))) float f32x4;

typedef const __attribute__((address_space(1))) u32* gp_t;
typedef __attribute__((address_space(3))) u32* lp_t;

__device__ __forceinline__ u32 f2bf1(float f) {
    u32 u = __float_as_uint(f);
    return (u + 0x7FFFu + ((u >> 16) & 1u)) >> 16;   // RNE
}
__device__ __forceinline__ u32 pack2(float a, float b) {
    return f2bf1(a) | (f2bf1(b) << 16);
}
__device__ __forceinline__ float bf2f(u16 h) {
    return __uint_as_float((u32)h << 16);
}

// ---------------- cvt Wk/Ww/Wv fp32->bf16  (+ folded BN prep in block 0) ----------------
__global__ __launch_bounds__(256) void cvt_w_kernel(
    const float* __restrict__ Wk, const float* __restrict__ Ww, const float* __restrict__ Wv,
    u16* __restrict__ Wkbf, u16* __restrict__ Wwbf, u16* __restrict__ Wvbf,
    const float* __restrict__ bk, const float* __restrict__ gamma,
    const float* __restrict__ beta, const float* __restrict__ rmean,
    const float* __restrict__ rvar, float* __restrict__ inv_out, float* __restrict__ bc_out)
{
    int j = (blockIdx.x * 256 + threadIdx.x) * 4;   // grid 384 -> 393216 elems
    const float* s; u16* d;
    if (j < KC * CIN)          { s = Wk; d = Wkbf; }
    else if (j < 2 * KC * CIN) { j -= KC * CIN;     s = Ww; d = Wwbf; }
    else                       { j -= 2 * KC * CIN; s = Wv; d = Wvbf; }
    float4 v = *(const float4*)&s[j];
    uint2 u;
    u.x = pack2(v.x, v.y);
    u.y = pack2(v.z, v.w);
    *(uint2*)&d[j] = u;
    if (blockIdx.x == 0) {   // folded prep: one thread per Kc channel
        const int i = threadIdx.x;
        float inv = gamma[i] * rsqrtf(rvar[i] + 1e-5f);
        inv_out[i] = inv;
        bc_out[i]  = bk[i] * inv + beta[i] - rmean[i] * inv;
    }
}

// ---------------- transpose+cvt 64x64: in [z][C][5184] f32 -> out [z][5184][C] bf16 ----------------
__global__ __launch_bounds__(256) void transpose_cvt_kernel(
    const float* __restrict__ in, u16* __restrict__ out, int C)
{
    const int z  = blockIdx.z;
    const int n0 = blockIdx.x * 64;   // HW
    const int k0 = blockIdx.y * 64;   // C
    __shared__ float t[64][65];
    const int tx = threadIdx.x & 63, ty = threadIdx.x >> 6;   // ty 0..3
    const float* src = in + ((size_t)z * C + k0) * HW + n0;
#pragma unroll
    for (int i = 0; i < 16; i++)
        t[ty + i * 4][tx] = src[(size_t)(ty + i * 4) * HW + tx];   // 256B segments
    __syncthreads();
    u16* dst = out + ((size_t)z * HW + n0) * C + k0;
    const int kp  = (threadIdx.x & 31) * 2;
    const int nl0 = threadIdx.x >> 5;           // 0..7
#pragma unroll
    for (int j = 0; j < 8; j++) {
        int nl = nl0 + j * 8;
        u32 u = pack2(t[kp][nl], t[kp + 1][nl]);
        *(u32*)&dst[(size_t)nl * C + kp] = u;   // 128B segments
    }
}

// ---------------- bf16 MFMA NT-GEMM, counted-vmcnt 3-buffer pipeline ----------------
__global__ __launch_bounds__(256) void gemm_nt_bf16(
    const u16* __restrict__ A, const u16* __restrict__ B, float* __restrict__ C,
    u16* __restrict__ Ct,
    int M, int N, int K, int nbx, int nby,
    const float* __restrict__ scale, const float* __restrict__ bias, int relu)
{
    const int tot = nbx * nby * BATCH;
    const int q = tot >> 3, r = tot & 7;
    const int xcd = blockIdx.x & 7;
    const int wg  = (xcd < r ? xcd * (q + 1) : r * (q + 1) + (xcd - r) * q) + (blockIdx.x >> 3);
    const int mb_ = wg % nby;
    const int nb_ = (wg / nby) % nbx;
    const int z   = wg / (nby * nbx);

    const int n0 = nb_ * 128;
    const int m0 = mb_ * 128;
    const size_t boff = (size_t)z * N * K;
    const size_t coff = (size_t)z * M * N;
    const int tid  = threadIdx.x;
    const int wid  = tid >> 6;
    const int lane = tid & 63;

    __shared__ __align__(16) u16 As[3][4][128][8];
    __shared__ __align__(16) u16 Bs[3][4][128][8];

    const int kg0  = (wid & 1) * 2;
    const int half = (wid >> 1) * 64;

    const u16* gA = A + (size_t)(m0 + half + lane) * K + kg0 * 8;
    int nIdx = n0 + half + lane;
    if (nIdx > N - 1) nIdx = N - 1;
    const u16* gB = B + boff + (size_t)nIdx * K + kg0 * 8;

    const int wm  = (wid >> 1) * 64;
    const int wn  = (wid & 1) * 64;
    const int l16 = lane & 15;
    const int lq  = lane >> 4;

    f32x4 acc[4][4];
#pragma unroll
    for (int mi = 0; mi < 4; mi++)
#pragma unroll
        for (int ni = 0; ni < 4; ni++)
            acc[mi][ni] = (f32x4){0.f, 0.f, 0.f, 0.f};

#define STAGE(d, kk)                                                                              \
    __builtin_amdgcn_global_load_lds((gp_t)(gA + (kk)),     (lp_t)&As[d][kg0][half][0], 16, 0, 0);\
    __builtin_amdgcn_global_load_lds((gp_t)(gA + (kk) + 8), (lp_t)&As[d][kg0+1][half][0],16, 0, 0);\
    __builtin_amdgcn_global_load_lds((gp_t)(gB + (kk)),     (lp_t)&Bs[d][kg0][half][0], 16, 0, 0);\
    __builtin_amdgcn_global_load_lds((gp_t)(gB + (kk) + 8), (lp_t)&Bs[d][kg0+1][half][0],16, 0, 0);

    const int NT = K >> 5;
    STAGE(0, 0)
    STAGE(1, 32)

    int cur = 0;
    for (int t = 0; t < NT; ++t) {
        if (t + 1 < NT) { asm volatile("s_waitcnt vmcnt(4)" ::: "memory"); }
        else            { asm volatile("s_waitcnt vmcnt(0)" ::: "memory"); }
        __builtin_amdgcn_s_barrier();
        __builtin_amdgcn_sched_barrier(0);

        if (t + 2 < NT) {
            int nb = cur + 2; if (nb >= 3) nb -= 3;
            STAGE(nb, (t + 2) * 32)
        }

        bf16x8 af[4], bf[4];
#pragma unroll
        for (int i = 0; i < 4; i++) {
            af[i] = *(const bf16x8*)&As[cur][lq][wm + i * 16 + l16][0];
            bf[i] = *(const bf16x8*)&Bs[cur][lq][wn + i * 16 + l16][0];
        }
        __builtin_amdgcn_s_setprio(1);
#pragma unroll
        for (int mi = 0; mi < 4; mi++)
#pragma unroll
            for (int ni = 0; ni < 4; ni++)
                acc[mi][ni] = __builtin_amdgcn_mfma_f32_16x16x32_bf16(
                    af[mi], bf[ni], acc[mi][ni], 0, 0, 0);
        __builtin_amdgcn_s_setprio(0);

        cur = (cur == 2) ? 0 : cur + 1;
    }
#undef STAGE

#pragma unroll
    for (int mi = 0; mi < 4; mi++) {
        const int mb = m0 + wm + mi * 16 + lq * 4;
        float sc[4], bi[4];
#pragma unroll
        for (int r2 = 0; r2 < 4; r2++) {
            sc[r2] = scale ? scale[mb + r2] : 1.0f;
            bi[r2] = bias  ? bias[mb + r2]  : 0.0f;
        }
#pragma unroll
        for (int ni = 0; ni < 4; ni++) {
            const int n = n0 + wn + ni * 16 + l16;
            if (n < N) {
                float v[4];
#pragma unroll
                for (int r2 = 0; r2 < 4; r2++) {
                    v[r2] = acc[mi][ni][r2] * sc[r2] + bi[r2];
                    if (relu) v[r2] = fmaxf(v[r2], 0.f);
                }
                if (C) {
#pragma unroll
                    for (int r2 = 0; r2 < 4; r2++)
                        C[coff + (size_t)(mb + r2) * N + n] = v[r2];
                }
                if (Ct) {
                    uint2 u;
                    u.x = pack2(v[0], v[1]);
                    u.y = pack2(v[2], v[3]);
                    *(uint2*)&Ct[(size_t)z * N * M + (size_t)n * M + mb] = u;
                }
            }
        }
    }
}

// ---------------- row pooling over kT: [b][5184][256] bf16 -> rp [b][72][15][256] f32 ----------------
__global__ __launch_bounds__(256) void rowpool_k_kernel(
    const u16* __restrict__ kT, float* __restrict__ rp)
{
    const int y = blockIdx.x;
    const int b = blockIdx.y;
    const int c = threadIdx.x;
    const u16* src = kT + ((size_t)b * HW + (size_t)y * WIDTH) * KC + c;
    float s9[8]  = {0.f, 0.f, 0.f, 0.f, 0.f, 0.f, 0.f, 0.f};
    float s12[6] = {0.f, 0.f, 0.f, 0.f, 0.f, 0.f};
#pragma unroll
    for (int x = 0; x < 72; x++) {
        float v = bf2f(src[(size_t)x * KC]);
        s9[x / 9] += v;
        s12[x / 12] += v;
    }
    float* dst = rp + (((size_t)b * 72 + y) * 15) * KC + c;
    float tot = 0.f;
#pragma unroll
    for (int g = 0; g < 8; g++) dst[(size_t)g * KC] = s9[g];
#pragma unroll
    for (int g = 0; g < 6; g++) { dst[(size_t)(8 + g) * KC] = s12[g]; tot += s12[g]; }
    dst[(size_t)14 * KC] = tot;
}

// ---------------- bin pooling: rp -> keytb [b][112][256] bf16 SWIZZLED ----------------
__global__ __launch_bounds__(256) void binpool_k_kernel(
    const float* __restrict__ rp, u16* __restrict__ keytb)
{
    const int s = blockIdx.x;
    const int b = blockIdx.y;
    const int c = threadIdx.x;
    char* ob = (char*)keytb + (size_t)b * NSP * KC * 2;
    float sum = 0.f, scl = 0.f;
    const float* rpb = rp + (size_t)b * 72 * 15 * KC + c;
    if (s < NS) {
        if (s == 0) {
#pragma unroll 8
            for (int y = 0; y < 72; y++) sum += rpb[((size_t)y * 15 + 14) * KC];
            scl = 1.f / 5184.f;
        } else if (s < 10) {
            const int t = s - 1, gy = t / 3, gx = t - gy * 3;
#pragma unroll 8
            for (int i = 0; i < 24; i++) {
                const int y = gy * 24 + i;
                sum += rpb[((size_t)y * 15 + 8 + 2 * gx) * KC]
                     + rpb[((size_t)y * 15 + 9 + 2 * gx) * KC];
            }
            scl = 1.f / 576.f;
        } else if (s < 46) {
            const int t = s - 10, gy = t / 6, gx = t - gy * 6;
#pragma unroll
            for (int i = 0; i < 12; i++) {
                const int y = gy * 12 + i;
                sum += rpb[((size_t)y * 15 + 8 + gx) * KC];
            }
            scl = 1.f / 144.f;
        } else {
            const int t = s - 46, gy = t >> 3, gx = t & 7;
#pragma unroll
            for (int i = 0; i < 9; i++) {
                const int y = gy * 9 + i;
                sum += rpb[((size_t)y * 15 + gx) * KC];
            }
            scl = 1.f / 81.f;
        }
    }
    const int byte = s * 512 + ((c * 2) ^ ((s & 7) << 4));
    *(u16*)(ob + byte) = (s < NS) ? (u16)f2bf1(sum * scl) : (u16)0;
}

// ---------------- value MFMA GEMM: valT SWIZZLED [b][v][s] bf16 ----------------
__global__ __launch_bounds__(256) void value_mfma_kernel(
    const u16* __restrict__ A, const u16* __restrict__ Bp,
    const float* __restrict__ bv, u16* __restrict__ valT)
{
    const int m0 = blockIdx.x * 128;
    const int b  = blockIdx.y;
    const int tid  = threadIdx.x;
    const int wid  = tid >> 6;
    const int lane = tid & 63;

    __shared__ __align__(16) u16 As[4][128][8];
    __shared__ __align__(16) u16 Bs[4][128][8];

    const int kg0  = (wid & 1) * 2;
    const int half = (wid >> 1) * 64;

    const u16* gA = A + (size_t)(m0 + half + lane) * CIN + kg0 * 8;
    const u16* gB = Bp + (size_t)b * SPV * CIN + (size_t)(half + lane) * CIN + kg0 * 8;

    lp_t lA0 = (lp_t)&As[kg0][half][0];
    lp_t lA1 = (lp_t)&As[kg0 + 1][half][0];
    lp_t lB0 = (lp_t)&Bs[kg0][half][0];
    lp_t lB1 = (lp_t)&Bs[kg0 + 1][half][0];

    const int wm  = (wid >> 1) * 64;
    const int wn  = (wid & 1) * 64;
    const int l16 = lane & 15;
    const int lq  = lane >> 4;

    f32x4 acc[4][4];
#pragma unroll
    for (int mi = 0; mi < 4; mi++)
#pragma unroll
        for (int ni = 0; ni < 4; ni++)
            acc[mi][ni] = (f32x4){0.f, 0.f, 0.f, 0.f};

    for (int k0 = 0; k0 < CIN; k0 += 32) {
        __builtin_amdgcn_global_load_lds((gp_t)(gA + k0),     lA0, 16, 0, 0);
        __builtin_amdgcn_global_load_lds((gp_t)(gA + k0 + 8), lA1, 16, 0, 0);
        __builtin_amdgcn_global_load_lds((gp_t)(gB + k0),     lB0, 16, 0, 0);
        __builtin_amdgcn_global_load_lds((gp_t)(gB + k0 + 8), lB1, 16, 0, 0);
        __syncthreads();

        bf16x8 af[4], bf[4];
#pragma unroll
        for (int i = 0; i < 4; i++) {
            af[i] = *(const bf16x8*)&As[lq][wm + i * 16 + l16][0];
            bf[i] = *(const bf16x8*)&Bs[lq][wn + i * 16 + l16][0];
        }
#pragma unroll
        for (int mi = 0; mi < 4; mi++)
#pragma unroll
            for (int ni = 0; ni < 4; ni++)
                acc[mi][ni] = __builtin_amdgcn_mfma_f32_16x16x32_bf16(
                    af[mi], bf[ni], acc[mi][ni], 0, 0, 0);
        __syncthreads();
    }

    char* vb = (char*)valT + (size_t)b * VC * SPV * 2;
#pragma unroll
    for (int mi = 0; mi < 4; mi++) {
        const int mb = m0 + wm + mi * 16 + lq * 4;
        float bi[4];
#pragma unroll
        for (int r = 0; r < 4; r++) bi[r] = bv[mb + r];
#pragma unroll
        for (int ni = 0; ni < 4; ni++) {
            const int n = wn + ni * 16 + l16;
#pragma unroll
            for (int r = 0; r < 4; r++) {
                const int v = mb + r;
                const int byte = v * 256 + ((n * 2) ^ ((v & 7) << 4));
                *(u16*)(vb + byte) = (u16)f2bf1(acc[mi][ni][r] + bi[r]);
            }
        }
    }
}

// ---------------- PSP pooling px: x [b][512][5184] f32 -> pxb [b][128][512] bf16 ----------------
__global__ __launch_bounds__(128) void psp_pool_px_kernel(
    const float* __restrict__ in, u16* __restrict__ out)
{
    const int c = blockIdx.x;   // 0..511
    const int b = blockIdx.y;
    const int t = threadIdx.x;
    __shared__ float4 row4[1296];
    __shared__ float aux[100];
    float* row = (float*)row4;
    const float* src = in + ((size_t)b * CIN + c) * HW;
    for (int idx = t; idx < 1296; idx += 128)
        row4[idx] = *(const float4*)(src + idx * 4);
    __syncthreads();
    if (t < 64) {
        int r0 = (t >> 3) * 9, c0 = (t & 7) * 9;
        float s = 0.f;
        for (int i = 0; i < 9; i++)
            for (int j = 0; j < 9; j++) s += row[(r0 + i) * WIDTH + c0 + j];
        aux[t] = s;
    } else if (t < 100) {
        int tt = t - 64;
        int r0 = (tt / 6) * 12, c0 = (tt % 6) * 12;
        float s = 0.f;
        for (int i = 0; i < 12; i++)
            for (int j = 0; j < 12; j++) s += row[(r0 + i) * WIDTH + c0 + j];
        aux[64 + tt] = s;
    }
    __syncthreads();
    u16* ob = out + (size_t)b * SPV * CIN + c;
    if (t < 64) ob[(size_t)(46 + t) * CIN] = (u16)f2bf1(aux[t] * (1.f / 81.f));
    if (t < 36) ob[(size_t)(10 + t) * CIN] = (u16)f2bf1(aux[64 + t] * (1.f / 144.f));
    if (t < 9) {
        int r = t / 3, cc = t % 3;
        float s4 = aux[64 + (2 * r) * 6 + 2 * cc] + aux[64 + (2 * r) * 6 + 2 * cc + 1]
                 + aux[64 + (2 * r + 1) * 6 + 2 * cc] + aux[64 + (2 * r + 1) * 6 + 2 * cc + 1];
        ob[(size_t)(1 + t) * CIN] = (u16)f2bf1(s4 * (1.f / 576.f));
    }
    if (t == 0) {
        float s = 0.f;
        for (int i = 0; i < 64; i++) s += aux[i];
        ob[0] = (u16)f2bf1(s * (1.f / 5184.f));
    }
    if (t < 18) ob[(size_t)(110 + t) * CIN] = 0;   // zero pad rows
}

// ---------------- MFMA attention + FUSED output GEMM, 48 KB LDS (3 blocks/CU) ----------------
// Pipelined 16 KB chunk staging: K in 4 chunks (32/32/32/16 rows), V in 4 chunks (64 rows),
// double-buffered in the 32K region (A=base+0, B=base+16K); chunk c+1 issued right after
// phase-c barrier -> stage latency hides under MFMA. P 16K at [32K,48K) (epilogue scratch).
__global__ __launch_bounds__(256, 3) void attn_mfma_kernel(
    const u16* __restrict__ qT, const u16* __restrict__ keyt,
    const u16* __restrict__ valT, const u16* __restrict__ Wwb,
    const float* __restrict__ bw, float* __restrict__ out)
{
    const int b    = blockIdx.y;
    const int tid  = threadIdx.x;
    const int wid  = tid >> 6;
    const int lane = tid & 63;
    const int l16  = lane & 15;
    const int lq   = lane >> 4;
    const int nblk = blockIdx.x * 64;              // block's 64-px base
    const int px0  = nblk + wid * 16;              // wave's 16-px row base

    __shared__ __align__(16) u16 SM[24576];        // 48 KiB -> 3 blocks/CU
    char* base = (char*)SM;
    const int POFF = 32768;                        // P region [32K,48K)

    const char* gk = (const char*)keyt + (size_t)b * (NSP * KC * 2);
    const char* gv = (const char*)valT + (size_t)b * (VC * SPV * 2);

    // ---- prologue: stage K chunk0 (s 0..31, 16K) -> bufA ----
#pragma unroll
    for (int i = 0; i < 4; i++) {
        const int o = (wid * 4 + i) * 1024;
        __builtin_amdgcn_global_load_lds((gp_t)(gk + o + lane * 16), (lp_t)(base + o), 16, 0, 0);
    }

    // ---- preload all 8 q fragments ----
    const u16* qrow = qT + ((size_t)b * HW + px0 + l16) * KC + lq * 8;
    bf16x8 aq[8];
#pragma unroll
    for (int ks = 0; ks < 8; ks++) aq[ks] = *(const bf16x8*)(qrow + ks * 32);

    // ==== QK^T: 4 pipelined chunks; chunk c holds s rows 32c..; acc[2c+j] ====
    f32x4 acc[7];
#pragma unroll
    for (int ni = 0; ni < 7; ni++) acc[ni] = (f32x4){0.f, 0.f, 0.f, 0.f};

#pragma unroll
    for (int c = 0; c < 4; c++) {
        asm volatile("s_waitcnt vmcnt(0)" ::: "memory");
        __builtin_amdgcn_s_barrier();
        __builtin_amdgcn_sched_barrier(0);
        char* cb = base + ((c & 1) ? 16384 : 0);
        char* nb = base + ((c & 1) ? 0 : 16384);
        if (c < 3) {            // stage K chunk c+1 into the other buffer (freed at this barrier)
            const int insts = (c + 1 < 3) ? 4 : 2;   // chunk3 is 8 KB
#pragma unroll
            for (int i = 0; i < insts; i++) {
                const int o = (wid * insts + i) * 1024;
                __builtin_amdgcn_global_load_lds(
                    (gp_t)(gk + (c + 1) * 16384 + o + lane * 16), (lp_t)(nb + o), 16, 0, 0);
            }
        } else {                // last K phase: stage V chunk0 (v 0..63, 16K) into other buffer
#pragma unroll
            for (int i = 0; i < 4; i++) {
                const int o = (wid * 4 + i) * 1024;
                __builtin_amdgcn_global_load_lds(
                    (gp_t)(gv + o + lane * 16), (lp_t)(nb + o), 16, 0, 0);
            }
        }
        __builtin_amdgcn_s_setprio(1);
        const int nj = (c < 3) ? 2 : 1;
#pragma unroll
        for (int ks = 0; ks < 8; ks++) {
#pragma unroll
            for (int j = 0; j < 2; j++) {
                if (j < nj) {
                    const int rl = j * 16 + l16;     // row within chunk
                    const int byte = rl * 512 + ((ks * 64 + lq * 16) ^ ((rl & 7) << 4));
                    bf16x8 bk = *(const bf16x8*)(cb + byte);
                    acc[2 * c + j] = __builtin_amdgcn_mfma_f32_16x16x32_bf16(
                        aq[ks], bk, acc[2 * c + j], 0, 0, 0);
                }
            }
        }
        __builtin_amdgcn_s_setprio(0);
    }
    if (l16 >= 14) acc[6] = (f32x4){-1e30f, -1e30f, -1e30f, -1e30f};  // mask s=110,111

    // ==== softmax (in-register), P writes to own region; V chunk0 flies underneath ====
    float mx[4], sm[4], rn[4];
#pragma unroll
    for (int r = 0; r < 4; r++) {
        float m = acc[0][r];
#pragma unroll
        for (int ni = 1; ni < 7; ni++) m = fmaxf(m, acc[ni][r]);
        m = fmaxf(m, __shfl_xor(m, 1));
        m = fmaxf(m, __shfl_xor(m, 2));
        m = fmaxf(m, __shfl_xor(m, 4));
        m = fmaxf(m, __shfl_xor(m, 8));
        mx[r] = m * 0.0625f;
        sm[r] = 0.f;
    }

    const int prow = wid * 16 + 4 * lq;
#pragma unroll
    for (int ni = 0; ni < 7; ni++) {
#pragma unroll
        for (int r = 0; r < 4; r++) {
            float p = __expf(acc[ni][r] * 0.0625f - mx[r]);
            sm[r] += p;
            const int row = prow + r;
            const int byte = POFF + row * 256 + (((ni * 16 + l16) * 2) ^ ((row & 7) << 4));
            *(u16*)(base + byte) = (u16)f2bf1(p);
        }
    }
    if (l16 < 2) {   // zero pad cols 112..127
#pragma unroll
        for (int r = 0; r < 4; r++) {
            const int row = prow + r;
            const int byte = POFF + row * 256 + ((224 + l16 * 16) ^ ((row & 7) << 4));
            *(bf16x8*)(base + byte) = (bf16x8){0, 0, 0, 0, 0, 0, 0, 0};
        }
    }
#pragma unroll
    for (int r = 0; r < 4; r++) {
        float s = sm[r];
        s += __shfl_xor(s, 1);
        s += __shfl_xor(s, 2);
        s += __shfl_xor(s, 4);
        s += __shfl_xor(s, 8);
        rn[r] = 1.f / s;
    }

    // ==== PV: 4 pipelined chunks of 64 v-rows; chunk c in buf[(c+?)]: chunk0 landed
    // in the buffer opposite K-chunk3, i.e. parity (K c=3 used B if ... ) -> track parity:
    // K chunk3 computed from buf[3&1]=B(base+16K), so V0 went to A(base+0): V chunk c in buf[c&1].
    f32x4 acc2[16];
#pragma unroll
    for (int ni = 0; ni < 16; ni++) acc2[ni] = (f32x4){0.f, 0.f, 0.f, 0.f};
    const int arow = wid * 16 + l16;
    const int aswz = (arow & 7) << 4;

#pragma unroll
    for (int c = 0; c < 4; c++) {
        asm volatile("s_waitcnt vmcnt(0)" ::: "memory");
        __builtin_amdgcn_s_barrier();        // also publishes P on c==0
        __builtin_amdgcn_sched_barrier(0);
        char* cb = base + ((c & 1) ? 16384 : 0);
        char* nb = base + ((c & 1) ? 0 : 16384);
        if (c < 3) {            // stage V chunk c+1
#pragma unroll
            for (int i = 0; i < 4; i++) {
                const int o = (wid * 4 + i) * 1024;
                __builtin_amdgcn_global_load_lds(
                    (gp_t)(gv + (c + 1) * 16384 + o + lane * 16), (lp_t)(nb + o), 16, 0, 0);
            }
        }
        __builtin_amdgcn_s_setprio(1);
#pragma unroll
        for (int ks = 0; ks < 4; ks++) {
            const int pbyte = POFF + arow * 256 + ((ks * 64 + lq * 16) ^ aswz);
            bf16x8 pa = *(const bf16x8*)(base + pbyte);
#pragma unroll
            for (int j = 0; j < 4; j++) {
                const int rl = j * 16 + l16;     // row within chunk (v - 64c)
                const int vbyte = rl * 256 + ((ks * 64 + lq * 16) ^ ((rl & 7) << 4));
                bf16x8 bvv = *(const bf16x8*)(cb + vbyte);
                acc2[4 * c + j] = __builtin_amdgcn_mfma_f32_16x16x32_bf16(
                    pa, bvv, acc2[4 * c + j], 0, 0, 0);
            }
        }
        __builtin_amdgcn_s_setprio(0);
    }
    __syncthreads();   // all PV done: both buffers + P dead

    // ---- write normalized ctx bf16 [64px][256v] swizzled into buf (32K exactly) ----
#pragma unroll
    for (int ni = 0; ni < 16; ni++) {
#pragma unroll
        for (int r = 0; r < 4; r++) {
            const int row = prow + r;
            const int v = ni * 16 + l16;
            const int byte = row * 512 + ((v * 2) ^ ((row & 7) << 4));
            *(u16*)(base + byte) = (u16)f2bf1(acc2[ni][r] * rn[r]);
        }
    }
    __syncthreads();   // ctx ready

    // ==== fused out-GEMM in 2 c-halves of 64 (VGPR cap for 3 waves/SIMD) ====
    const int wc0 = wid * 128;
    float* outb = out + (size_t)b * CIN * HW + nblk;
    char* scr = base + POFF + wid * 4096;   // 4 KB/wave transpose scratch (P region, dead)

#pragma unroll
    for (int ch = 0; ch < 2; ch++) {
        f32x4 accg[4][4];   // [pi: px-tile][cj: c-tile of 16]
#pragma unroll
        for (int pi = 0; pi < 4; pi++)
#pragma unroll
            for (int cj = 0; cj < 4; cj++)
                accg[pi][cj] = (f32x4){0.f, 0.f, 0.f, 0.f};

        const u16* wwbase = Wwb + (size_t)(wc0 + ch * 64 + l16) * VC + lq * 8;
        __builtin_amdgcn_s_setprio(1);
#pragma unroll
        for (int ks = 0; ks < 8; ks++) {
            bf16x8 af[4];
#pragma unroll
            for (int pi = 0; pi < 4; pi++) {
                const int px = pi * 16 + l16;
                const int byte = px * 512 + ((ks * 64 + lq * 16) ^ ((px & 7) << 4));
                af[pi] = *(const bf16x8*)(base + byte);
            }
            bf16x8 bfr[4];
#pragma unroll
            for (int cj = 0; cj < 4; cj++)
                bfr[cj] = *(const bf16x8*)(wwbase + (size_t)cj * 16 * VC + ks * 32);
#pragma unroll
            for (int pi = 0; pi < 4; pi++)
#pragma unroll
                for (int cj = 0; cj < 4; cj++)
                    accg[pi][cj] = __builtin_amdgcn_mfma_f32_16x16x32_bf16(
                        af[pi], bfr[cj], accg[pi][cj], 0, 0, 0);
        }
        __builtin_amdgcn_s_setprio(0);

        // epilogue for these 64 c: per cj-tile of 16, wave-private LDS transpose
#pragma unroll
        for (int cj = 0; cj < 4; cj++) {
            const int cl = l16;                 // c-local row 0..15
            const int swz = (cl & 7) << 5;
#pragma unroll
            for (int pi = 0; pi < 4; pi++)
#pragma unroll
                for (int r = 0; r < 4; r++) {
                    const int px = pi * 16 + 4 * lq + r;
                    *(float*)(scr + cl * 256 + ((px * 4) ^ swz)) = accg[pi][cj][r];
                }
#pragma unroll
            for (int cr = 0; cr < 4; cr++) {
                const int cl2 = cr * 4 + lq;
                const int swz2 = (cl2 & 7) << 5;
                float4 vv = *(const float4*)(scr + cl2 * 256 + ((l16 * 16) ^ swz2));
                const int c = wc0 + ch * 64 + cj * 16 + cl2;
                const float bb = bw[c];
                vv.x += bb; vv.y += bb; vv.z += bb; vv.w += bb;
                *(float4*)&outb[(size_t)c * HW + l16 * 4] = vv;
            }
        }
    }
}

extern "C" void kernel_launch(void* const* d_in, const int* in_sizes, int n_in,
                              void* d_out, int out_size, void* d_ws, size_t ws_size,
                              hipStream_t stream)
{
    const float* x     = (const float*)d_in[0];
    const float* Wk    = (const float*)d_in[1];
    const float* bk    = (const float*)d_in[2];
    const float* gamma = (const float*)d_in[3];
    const float* beta  = (const float*)d_in[4];
    const float* rmean = (const float*)d_in[5];
    const float* rvar  = (const float*)d_in[6];
    const float* Wv    = (const float*)d_in[7];
    const float* bv    = (const float*)d_in[8];
    const float* Ww    = (const float*)d_in[9];
    const float* bw    = (const float*)d_in[10];
    float* out = (float*)d_out;

    float* ws    = (float*)d_ws;
    float* rpk   = ws;                                        // [8][72][15][256] f32
    u16*   xT    = (u16*)(rpk + (size_t)BATCH * 72 * 15 * KC); // [8][5184][512] bf16
    u16*   kT    = xT + (size_t)BATCH * HW * CIN;             // [8][5184][256] bf16
    u16*   pxb   = kT + (size_t)BATCH * HW * KC;              // [8][128][512] bf16
    u16*   keytb = pxb + (size_t)BATCH * SPV * CIN;           // [8][112][256] bf16 (swizzled)
    u16*   valT  = keytb + (size_t)BATCH * NSP * KC;          // [8][256][128] bf16 (swizzled)
    u16*   Wkbf  = valT + (size_t)BATCH * VC * SPV;           // [256][512] bf16
    u16*   Wwbf  = Wkbf + (size_t)KC * CIN;                   // [512][256] bf16
    u16*   Wvbf  = Wwbf + (size_t)CIN * VC;                   // [256][512] bf16
    float* inv   = (float*)(Wvbf + (size_t)KC * CIN);         // [256]
    float* bc    = inv + 256;                                 // [256]

    cvt_w_kernel<<<384, 256, 0, stream>>>(Wk, Ww, Wv, Wkbf, Wwbf, Wvbf,
                                          bk, gamma, beta, rmean, rvar, inv, bc);
    psp_pool_px_kernel<<<dim3(CIN, BATCH), 128, 0, stream>>>(x, pxb);
    transpose_cvt_kernel<<<dim3(HW / 64, CIN / 64, BATCH), 256, 0, stream>>>(x, xT, CIN);
    // k = relu(BN(Wk @ x)) : bf16 kT only (pooling runs off kT)
    {
        const int nbx = (HW + 127) / 128, nby = KC / 128;
        gemm_nt_bf16<<<nbx * nby * BATCH, 256, 0, stream>>>(
            Wkbf, xT, nullptr, kT, KC, HW, CIN, nbx, nby, inv, bc, 1);
    }
    rowpool_k_kernel<<<dim3(72, BATCH), 256, 0, stream>>>(kT, rpk);
    binpool_k_kernel<<<dim3(NSP, BATCH), 256, 0, stream>>>(rpk, keytb);
    value_mfma_kernel<<<dim3(2, BATCH), 256, 0, stream>>>(Wvbf, pxb, bv, valT);
    // attention + fused out-GEMM (writes final output directly)
    attn_mfma_kernel<<<dim3(HW / 64, BATCH), 256, 0, stream>>>(
        kT, keytb, valT, Wwbf, bw, out);
}

// Round 16
// 157.766 us; speedup vs baseline: 1.0199x; 1.0199x over previous
//
#include <hip/hip_runtime.h>
#include <hip/hip_bf16.h>

#define HW    5184
#define WIDTH 72
#define CIN   512
#define KC    256
#define VC    256
#define NS    110
#define NSP   112   // padded s for QK^T (7*16)
#define SPV   128   // padded s for PV k-dim (4*32)
#define BATCH 8

typedef unsigned short u16;
typedef unsigned int   u32;
typedef __attribute__((ext_vector_type(8))) short bf16x8;   // 8 bf16 = 4 VGPRs
typedef __attribute__((ext_vector_type(4))) float f32x4;

typedef const __attribute__((address_space(1))) u32* gp_t;
typedef __attribute__((address_space(3))) u32* lp_t;

__device__ __forceinline__ u32 f2bf1(float f) {
    u32 u = __float_as_uint(f);
    return (u + 0x7FFFu + ((u >> 16) & 1u)) >> 16;   // RNE
}
__device__ __forceinline__ u32 pack2(float a, float b) {
    return f2bf1(a) | (f2bf1(b) << 16);
}
__device__ __forceinline__ float bf2f(u16 h) {
    return __uint_as_float((u32)h << 16);
}

// ---------------- prep: fold BN into per-channel scale/bias ----------------
__global__ void prep_kernel(const float* __restrict__ bk, const float* __restrict__ gamma,
                            const float* __restrict__ beta, const float* __restrict__ rmean,
                            const float* __restrict__ rvar, float* __restrict__ inv_out,
                            float* __restrict__ bc_out) {
    int i = threadIdx.x;  // 256 threads, one per Kc channel
    float inv = gamma[i] * rsqrtf(rvar[i] + 1e-5f);
    inv_out[i] = inv;
    bc_out[i]  = bk[i] * inv + beta[i] - rmean[i] * inv;
}

// ---------------- convert Wk/Ww/Wv fp32 -> bf16 ----------------
__global__ __launch_bounds__(256) void cvt_w_kernel(
    const float* __restrict__ Wk, const float* __restrict__ Ww, const float* __restrict__ Wv,
    u16* __restrict__ Wkbf, u16* __restrict__ Wwbf, u16* __restrict__ Wvbf)
{
    int j = (blockIdx.x * 256 + threadIdx.x) * 4;   // grid 384 -> 393216 elems
    const float* s; u16* d;
    if (j < KC * CIN)          { s = Wk; d = Wkbf; }
    else if (j < 2 * KC * CIN) { j -= KC * CIN;     s = Ww; d = Wwbf; }
    else                       { j -= 2 * KC * CIN; s = Wv; d = Wvbf; }
    float4 v = *(const float4*)&s[j];
    uint2 u;
    u.x = pack2(v.x, v.y);
    u.y = pack2(v.z, v.w);
    *(uint2*)&d[j] = u;
}

// ---------------- transpose+cvt 64x64: in [z][C][5184] f32 -> out [z][5184][C] bf16 ----------------
__global__ __launch_bounds__(256) void transpose_cvt_kernel(
    const float* __restrict__ in, u16* __restrict__ out, int C)
{
    const int z  = blockIdx.z;
    const int n0 = blockIdx.x * 64;   // HW
    const int k0 = blockIdx.y * 64;   // C
    __shared__ float t[64][65];
    const int tx = threadIdx.x & 63, ty = threadIdx.x >> 6;   // ty 0..3
    const float* src = in + ((size_t)z * C + k0) * HW + n0;
#pragma unroll
    for (int i = 0; i < 16; i++)
        t[ty + i * 4][tx] = src[(size_t)(ty + i * 4) * HW + tx];   // 256B segments
    __syncthreads();
    u16* dst = out + ((size_t)z * HW + n0) * C + k0;
    const int kp  = (threadIdx.x & 31) * 2;
    const int nl0 = threadIdx.x >> 5;           // 0..7
#pragma unroll
    for (int j = 0; j < 8; j++) {
        int nl = nl0 + j * 8;
        u32 u = pack2(t[kp][nl], t[kp + 1][nl]);
        *(u32*)&dst[(size_t)nl * C + kp] = u;   // 128B segments
    }
}

// ---------------- bf16 MFMA NT-GEMM, counted-vmcnt 3-buffer pipeline ----------------
__global__ __launch_bounds__(256) void gemm_nt_bf16(
    const u16* __restrict__ A, const u16* __restrict__ B, float* __restrict__ C,
    u16* __restrict__ Ct,
    int M, int N, int K, int nbx, int nby,
    const float* __restrict__ scale, const float* __restrict__ bias, int relu)
{
    const int tot = nbx * nby * BATCH;
    const int q = tot >> 3, r = tot & 7;
    const int xcd = blockIdx.x & 7;
    const int wg  = (xcd < r ? xcd * (q + 1) : r * (q + 1) + (xcd - r) * q) + (blockIdx.x >> 3);
    const int mb_ = wg % nby;
    const int nb_ = (wg / nby) % nbx;
    const int z   = wg / (nby * nbx);

    const int n0 = nb_ * 128;
    const int m0 = mb_ * 128;
    const size_t boff = (size_t)z * N * K;
    const size_t coff = (size_t)z * M * N;
    const int tid  = threadIdx.x;
    const int wid  = tid >> 6;
    const int lane = tid & 63;

    __shared__ __align__(16) u16 As[3][4][128][8];
    __shared__ __align__(16) u16 Bs[3][4][128][8];

    const int kg0  = (wid & 1) * 2;
    const int half = (wid >> 1) * 64;

    const u16* gA = A + (size_t)(m0 + half + lane) * K + kg0 * 8;
    int nIdx = n0 + half + lane;
    if (nIdx > N - 1) nIdx = N - 1;
    const u16* gB = B + boff + (size_t)nIdx * K + kg0 * 8;

    const int wm  = (wid >> 1) * 64;
    const int wn  = (wid & 1) * 64;
    const int l16 = lane & 15;
    const int lq  = lane >> 4;

    f32x4 acc[4][4];
#pragma unroll
    for (int mi = 0; mi < 4; mi++)
#pragma unroll
        for (int ni = 0; ni < 4; ni++)
            acc[mi][ni] = (f32x4){0.f, 0.f, 0.f, 0.f};

#define STAGE(d, kk)                                                                              \
    __builtin_amdgcn_global_load_lds((gp_t)(gA + (kk)),     (lp_t)&As[d][kg0][half][0], 16, 0, 0);\
    __builtin_amdgcn_global_load_lds((gp_t)(gA + (kk) + 8), (lp_t)&As[d][kg0+1][half][0],16, 0, 0);\
    __builtin_amdgcn_global_load_lds((gp_t)(gB + (kk)),     (lp_t)&Bs[d][kg0][half][0], 16, 0, 0);\
    __builtin_amdgcn_global_load_lds((gp_t)(gB + (kk) + 8), (lp_t)&Bs[d][kg0+1][half][0],16, 0, 0);

    const int NT = K >> 5;
    STAGE(0, 0)
    STAGE(1, 32)

    int cur = 0;
    for (int t = 0; t < NT; ++t) {
        if (t + 1 < NT) { asm volatile("s_waitcnt vmcnt(4)" ::: "memory"); }
        else            { asm volatile("s_waitcnt vmcnt(0)" ::: "memory"); }
        __builtin_amdgcn_s_barrier();
        __builtin_amdgcn_sched_barrier(0);

        if (t + 2 < NT) {
            int nb = cur + 2; if (nb >= 3) nb -= 3;
            STAGE(nb, (t + 2) * 32)
        }

        bf16x8 af[4], bf[4];
#pragma unroll
        for (int i = 0; i < 4; i++) {
            af[i] = *(const bf16x8*)&As[cur][lq][wm + i * 16 + l16][0];
            bf[i] = *(const bf16x8*)&Bs[cur][lq][wn + i * 16 + l16][0];
        }
        __builtin_amdgcn_s_setprio(1);
#pragma unroll
        for (int mi = 0; mi < 4; mi++)
#pragma unroll
            for (int ni = 0; ni < 4; ni++)
                acc[mi][ni] = __builtin_amdgcn_mfma_f32_16x16x32_bf16(
                    af[mi], bf[ni], acc[mi][ni], 0, 0, 0);
        __builtin_amdgcn_s_setprio(0);

        cur = (cur == 2) ? 0 : cur + 1;
    }
#undef STAGE

#pragma unroll
    for (int mi = 0; mi < 4; mi++) {
        const int mb = m0 + wm + mi * 16 + lq * 4;
        float sc[4], bi[4];
#pragma unroll
        for (int r2 = 0; r2 < 4; r2++) {
            sc[r2] = scale ? scale[mb + r2] : 1.0f;
            bi[r2] = bias  ? bias[mb + r2]  : 0.0f;
        }
#pragma unroll
        for (int ni = 0; ni < 4; ni++) {
            const int n = n0 + wn + ni * 16 + l16;
            if (n < N) {
                float v[4];
#pragma unroll
                for (int r2 = 0; r2 < 4; r2++) {
                    v[r2] = acc[mi][ni][r2] * sc[r2] + bi[r2];
                    if (relu) v[r2] = fmaxf(v[r2], 0.f);
                }
                if (C) {
#pragma unroll
                    for (int r2 = 0; r2 < 4; r2++)
                        C[coff + (size_t)(mb + r2) * N + n] = v[r2];
                }
                if (Ct) {
                    uint2 u;
                    u.x = pack2(v[0], v[1]);
                    u.y = pack2(v[2], v[3]);
                    *(uint2*)&Ct[(size_t)z * N * M + (size_t)n * M + mb] = u;
                }
            }
        }
    }
}

// ---------------- row pooling over kT: [b][5184][256] bf16 -> rp [b][72][15][256] f32 ----------------
__global__ __launch_bounds__(256) void rowpool_k_kernel(
    const u16* __restrict__ kT, float* __restrict__ rp)
{
    const int y = blockIdx.x;
    const int b = blockIdx.y;
    const int c = threadIdx.x;
    const u16* src = kT + ((size_t)b * HW + (size_t)y * WIDTH) * KC + c;
    float s9[8]  = {0.f, 0.f, 0.f, 0.f, 0.f, 0.f, 0.f, 0.f};
    float s12[6] = {0.f, 0.f, 0.f, 0.f, 0.f, 0.f};
#pragma unroll
    for (int x = 0; x < 72; x++) {
        float v = bf2f(src[(size_t)x * KC]);
        s9[x / 9] += v;
        s12[x / 12] += v;
    }
    float* dst = rp + (((size_t)b * 72 + y) * 15) * KC + c;
    float tot = 0.f;
#pragma unroll
    for (int g = 0; g < 8; g++) dst[(size_t)g * KC] = s9[g];
#pragma unroll
    for (int g = 0; g < 6; g++) { dst[(size_t)(8 + g) * KC] = s12[g]; tot += s12[g]; }
    dst[(size_t)14 * KC] = tot;
}

// ---------------- bin pooling: rp -> keytb [b][112][256] bf16 SWIZZLED ----------------
__global__ __launch_bounds__(256) void binpool_k_kernel(
    const float* __restrict__ rp, u16* __restrict__ keytb)
{
    const int s = blockIdx.x;
    const int b = blockIdx.y;
    const int c = threadIdx.x;
    char* ob = (char*)keytb + (size_t)b * NSP * KC * 2;
    float sum = 0.f, scl = 0.f;
    const float* rpb = rp + (size_t)b * 72 * 15 * KC + c;
    if (s < NS) {
        if (s == 0) {
#pragma unroll 8
            for (int y = 0; y < 72; y++) sum += rpb[((size_t)y * 15 + 14) * KC];
            scl = 1.f / 5184.f;
        } else if (s < 10) {
            const int t = s - 1, gy = t / 3, gx = t - gy * 3;
#pragma unroll 8
            for (int i = 0; i < 24; i++) {
                const int y = gy * 24 + i;
                sum += rpb[((size_t)y * 15 + 8 + 2 * gx) * KC]
                     + rpb[((size_t)y * 15 + 9 + 2 * gx) * KC];
            }
            scl = 1.f / 576.f;
        } else if (s < 46) {
            const int t = s - 10, gy = t / 6, gx = t - gy * 6;
#pragma unroll
            for (int i = 0; i < 12; i++) {
                const int y = gy * 12 + i;
                sum += rpb[((size_t)y * 15 + 8 + gx) * KC];
            }
            scl = 1.f / 144.f;
        } else {
            const int t = s - 46, gy = t >> 3, gx = t & 7;
#pragma unroll
            for (int i = 0; i < 9; i++) {
                const int y = gy * 9 + i;
                sum += rpb[((size_t)y * 15 + gx) * KC];
            }
            scl = 1.f / 81.f;
        }
    }
    const int byte = s * 512 + ((c * 2) ^ ((s & 7) << 4));
    *(u16*)(ob + byte) = (s < NS) ? (u16)f2bf1(sum * scl) : (u16)0;
}

// ---------------- value MFMA GEMM: valT SWIZZLED [b][v][s] bf16 ----------------
__global__ __launch_bounds__(256) void value_mfma_kernel(
    const u16* __restrict__ A, const u16* __restrict__ Bp,
    const float* __restrict__ bv, u16* __restrict__ valT)
{
    const int m0 = blockIdx.x * 128;
    const int b  = blockIdx.y;
    const int tid  = threadIdx.x;
    const int wid  = tid >> 6;
    const int lane = tid & 63;

    __shared__ __align__(16) u16 As[4][128][8];
    __shared__ __align__(16) u16 Bs[4][128][8];

    const int kg0  = (wid & 1) * 2;
    const int half = (wid >> 1) * 64;

    const u16* gA = A + (size_t)(m0 + half + lane) * CIN + kg0 * 8;
    const u16* gB = Bp + (size_t)b * SPV * CIN + (size_t)(half + lane) * CIN + kg0 * 8;

    lp_t lA0 = (lp_t)&As[kg0][half][0];
    lp_t lA1 = (lp_t)&As[kg0 + 1][half][0];
    lp_t lB0 = (lp_t)&Bs[kg0][half][0];
    lp_t lB1 = (lp_t)&Bs[kg0 + 1][half][0];

    const int wm  = (wid >> 1) * 64;
    const int wn  = (wid & 1) * 64;
    const int l16 = lane & 15;
    const int lq  = lane >> 4;

    f32x4 acc[4][4];
#pragma unroll
    for (int mi = 0; mi < 4; mi++)
#pragma unroll
        for (int ni = 0; ni < 4; ni++)
            acc[mi][ni] = (f32x4){0.f, 0.f, 0.f, 0.f};

    for (int k0 = 0; k0 < CIN; k0 += 32) {
        __builtin_amdgcn_global_load_lds((gp_t)(gA + k0),     lA0, 16, 0, 0);
        __builtin_amdgcn_global_load_lds((gp_t)(gA + k0 + 8), lA1, 16, 0, 0);
        __builtin_amdgcn_global_load_lds((gp_t)(gB + k0),     lB0, 16, 0, 0);
        __builtin_amdgcn_global_load_lds((gp_t)(gB + k0 + 8), lB1, 16, 0, 0);
        __syncthreads();

        bf16x8 af[4], bf[4];
#pragma unroll
        for (int i = 0; i < 4; i++) {
            af[i] = *(const bf16x8*)&As[lq][wm + i * 16 + l16][0];
            bf[i] = *(const bf16x8*)&Bs[lq][wn + i * 16 + l16][0];
        }
#pragma unroll
        for (int mi = 0; mi < 4; mi++)
#pragma unroll
            for (int ni = 0; ni < 4; ni++)
                acc[mi][ni] = __builtin_amdgcn_mfma_f32_16x16x32_bf16(
                    af[mi], bf[ni], acc[mi][ni], 0, 0, 0);
        __syncthreads();
    }

    char* vb = (char*)valT + (size_t)b * VC * SPV * 2;
#pragma unroll
    for (int mi = 0; mi < 4; mi++) {
        const int mb = m0 + wm + mi * 16 + lq * 4;
        float bi[4];
#pragma unroll
        for (int r = 0; r < 4; r++) bi[r] = bv[mb + r];
#pragma unroll
        for (int ni = 0; ni < 4; ni++) {
            const int n = wn + ni * 16 + l16;
#pragma unroll
            for (int r = 0; r < 4; r++) {
                const int v = mb + r;
                const int byte = v * 256 + ((n * 2) ^ ((v & 7) << 4));
                *(u16*)(vb + byte) = (u16)f2bf1(acc[mi][ni][r] + bi[r]);
            }
        }
    }
}

// ---------------- PSP pooling px: x [b][512][5184] f32 -> pxb [b][128][512] bf16 ----------------
__global__ __launch_bounds__(128) void psp_pool_px_kernel(
    const float* __restrict__ in, u16* __restrict__ out)
{
    const int c = blockIdx.x;   // 0..511
    const int b = blockIdx.y;
    const int t = threadIdx.x;
    __shared__ float4 row4[1296];
    __shared__ float aux[100];
    float* row = (float*)row4;
    const float* src = in + ((size_t)b * CIN + c) * HW;
    for (int idx = t; idx < 1296; idx += 128)
        row4[idx] = *(const float4*)(src + idx * 4);
    __syncthreads();
    if (t < 64) {
        int r0 = (t >> 3) * 9, c0 = (t & 7) * 9;
        float s = 0.f;
        for (int i = 0; i < 9; i++)
            for (int j = 0; j < 9; j++) s += row[(r0 + i) * WIDTH + c0 + j];
        aux[t] = s;
    } else if (t < 100) {
        int tt = t - 64;
        int r0 = (tt / 6) * 12, c0 = (tt % 6) * 12;
        float s = 0.f;
        for (int i = 0; i < 12; i++)
            for (int j = 0; j < 12; j++) s += row[(r0 + i) * WIDTH + c0 + j];
        aux[64 + tt] = s;
    }
    __syncthreads();
    u16* ob = out + (size_t)b * SPV * CIN + c;
    if (t < 64) ob[(size_t)(46 + t) * CIN] = (u16)f2bf1(aux[t] * (1.f / 81.f));
    if (t < 36) ob[(size_t)(10 + t) * CIN] = (u16)f2bf1(aux[64 + t] * (1.f / 144.f));
    if (t < 9) {
        int r = t / 3, cc = t % 3;
        float s4 = aux[64 + (2 * r) * 6 + 2 * cc] + aux[64 + (2 * r) * 6 + 2 * cc + 1]
                 + aux[64 + (2 * r + 1) * 6 + 2 * cc] + aux[64 + (2 * r + 1) * 6 + 2 * cc + 1];
        ob[(size_t)(1 + t) * CIN] = (u16)f2bf1(s4 * (1.f / 576.f));
    }
    if (t == 0) {
        float s = 0.f;
        for (int i = 0; i < 64; i++) s += aux[i];
        ob[0] = (u16)f2bf1(s * (1.f / 5184.f));
    }
    if (t < 18) ob[(size_t)(110 + t) * CIN] = 0;   // zero pad rows
}

// ---------------- MFMA attention + FUSED output GEMM, 48 KB LDS (3 blocks/CU) ----------------
// One 32K buffer time-multiplexed: K0(s0-63) -> K1(s64-111) -> V0(v0-127) -> V1(v128-255) -> ctx.
// P 16K at [32K,48K), doubles as 4KB/wave transpose scratch in epilogue.
// s_setprio(1) wrapped around all MFMA clusters (T5: phase-split schedule).
__global__ __launch_bounds__(256, 3) void attn_mfma_kernel(
    const u16* __restrict__ qT, const u16* __restrict__ keyt,
    const u16* __restrict__ valT, const u16* __restrict__ Wwb,
    const float* __restrict__ bw, float* __restrict__ out)
{
    const int b    = blockIdx.y;
    const int tid  = threadIdx.x;
    const int wid  = tid >> 6;
    const int lane = tid & 63;
    const int l16  = lane & 15;
    const int lq   = lane >> 4;
    const int nblk = blockIdx.x * 64;              // block's 64-px base
    const int px0  = nblk + wid * 16;              // wave's 16-px row base

    __shared__ __align__(16) u16 SM[24576];        // 48 KiB -> 3 blocks/CU
    char* base = (char*)SM;
    const int POFF = 32768;                        // P region [32K,48K)

    const char* gk = (const char*)keyt + (size_t)b * (NSP * KC * 2);
    const char* gv = (const char*)valT + (size_t)b * (VC * SPV * 2);

    // ---- stage K0 (s 0..63, 32K) ----
#pragma unroll
    for (int i = 0; i < 8; i++) {
        const int o = (wid * 8 + i) * 1024;
        __builtin_amdgcn_global_load_lds((gp_t)(gk + o + lane * 16), (lp_t)(base + o), 16, 0, 0);
    }

    // ---- preload all 8 q fragments (overlaps with staging drain) ----
    const u16* qrow = qT + ((size_t)b * HW + px0 + l16) * KC + lq * 8;
    bf16x8 aq[8];
#pragma unroll
    for (int ks = 0; ks < 8; ks++) aq[ks] = *(const bf16x8*)(qrow + ks * 32);

    __syncthreads();   // b1: K0 ready

    // ==== QK^T chunk0: ni 0..3 (s 0..63) ====
    f32x4 acc[7];
#pragma unroll
    for (int ni = 0; ni < 7; ni++) acc[ni] = (f32x4){0.f, 0.f, 0.f, 0.f};
    __builtin_amdgcn_s_setprio(1);
#pragma unroll
    for (int ks = 0; ks < 8; ks++) {
#pragma unroll
        for (int ni = 0; ni < 4; ni++) {
            const int s = ni * 16 + l16;
            const int byte = s * 512 + ((ks * 64 + lq * 16) ^ ((s & 7) << 4));
            bf16x8 bk = *(const bf16x8*)(base + byte);
            acc[ni] = __builtin_amdgcn_mfma_f32_16x16x32_bf16(aq[ks], bk, acc[ni], 0, 0, 0);
        }
    }
    __builtin_amdgcn_s_setprio(0);
    __syncthreads();   // b2: K0 dead

    // ---- stage K1 (s 64..111, 24K) ----
#pragma unroll
    for (int i = 0; i < 6; i++) {
        const int o = (wid * 6 + i) * 1024;
        __builtin_amdgcn_global_load_lds((gp_t)(gk + 32768 + o + lane * 16), (lp_t)(base + o), 16, 0, 0);
    }
    __syncthreads();   // b3: K1 ready

    // ==== QK^T chunk1: ni 4..6 (s 64..111; buf row = s-64) ====
    __builtin_amdgcn_s_setprio(1);
#pragma unroll
    for (int ks = 0; ks < 8; ks++) {
#pragma unroll
        for (int ni = 4; ni < 7; ni++) {
            const int s = ni * 16 + l16;
            const int srow = s - 64;
            const int byte = srow * 512 + ((ks * 64 + lq * 16) ^ ((srow & 7) << 4));
            bf16x8 bk = *(const bf16x8*)(base + byte);
            acc[ni] = __builtin_amdgcn_mfma_f32_16x16x32_bf16(aq[ks], bk, acc[ni], 0, 0, 0);
        }
    }
    __builtin_amdgcn_s_setprio(0);
    if (l16 >= 14) acc[6] = (f32x4){-1e30f, -1e30f, -1e30f, -1e30f};  // mask s=110,111
    __syncthreads();   // b4: K1 dead -> buf free for V0

    // ---- stage V0 (v 0..127, 32K) -- latency hides under softmax below ----
#pragma unroll
    for (int i = 0; i < 8; i++) {
        const int o = (wid * 8 + i) * 1024;
        __builtin_amdgcn_global_load_lds((gp_t)(gv + o + lane * 16), (lp_t)(base + o), 16, 0, 0);
    }

    // ==== softmax (in-register), P writes to own region ====
    float mx[4], sm[4], rn[4];
#pragma unroll
    for (int r = 0; r < 4; r++) {
        float m = acc[0][r];
#pragma unroll
        for (int ni = 1; ni < 7; ni++) m = fmaxf(m, acc[ni][r]);
        m = fmaxf(m, __shfl_xor(m, 1));
        m = fmaxf(m, __shfl_xor(m, 2));
        m = fmaxf(m, __shfl_xor(m, 4));
        m = fmaxf(m, __shfl_xor(m, 8));
        mx[r] = m * 0.0625f;
        sm[r] = 0.f;
    }

    const int prow = wid * 16 + 4 * lq;
#pragma unroll
    for (int ni = 0; ni < 7; ni++) {
#pragma unroll
        for (int r = 0; r < 4; r++) {
            float p = __expf(acc[ni][r] * 0.0625f - mx[r]);
            sm[r] += p;
            const int row = prow + r;
            const int byte = POFF + row * 256 + (((ni * 16 + l16) * 2) ^ ((row & 7) << 4));
            *(u16*)(base + byte) = (u16)f2bf1(p);
        }
    }
    if (l16 < 2) {   // zero pad cols 112..127
#pragma unroll
        for (int r = 0; r < 4; r++) {
            const int row = prow + r;
            const int byte = POFF + row * 256 + ((224 + l16 * 16) ^ ((row & 7) << 4));
            *(bf16x8*)(base + byte) = (bf16x8){0, 0, 0, 0, 0, 0, 0, 0};
        }
    }
#pragma unroll
    for (int r = 0; r < 4; r++) {
        float s = sm[r];
        s += __shfl_xor(s, 1);
        s += __shfl_xor(s, 2);
        s += __shfl_xor(s, 4);
        s += __shfl_xor(s, 8);
        rn[r] = 1.f / s;
    }
    __syncthreads();   // b5: V0 ready (vmcnt drained), P visible

    // ==== PV chunk0: ni 0..7 (v 0..127) ====
    f32x4 acc2[16];
#pragma unroll
    for (int ni = 0; ni < 16; ni++) acc2[ni] = (f32x4){0.f, 0.f, 0.f, 0.f};
    const int arow = wid * 16 + l16;
    const int aswz = (arow & 7) << 4;
    __builtin_amdgcn_s_setprio(1);
#pragma unroll
    for (int ks = 0; ks < 4; ks++) {
        const int pbyte = POFF + arow * 256 + ((ks * 64 + lq * 16) ^ aswz);
        bf16x8 pa = *(const bf16x8*)(base + pbyte);
#pragma unroll
        for (int ni = 0; ni < 8; ni++) {
            const int v = ni * 16 + l16;
            const int vbyte = v * 256 + ((ks * 64 + lq * 16) ^ ((v & 7) << 4));
            bf16x8 bvv = *(const bf16x8*)(base + vbyte);
            acc2[ni] = __builtin_amdgcn_mfma_f32_16x16x32_bf16(pa, bvv, acc2[ni], 0, 0, 0);
        }
    }
    __builtin_amdgcn_s_setprio(0);
    __syncthreads();   // b6: V0 dead

    // ---- stage V1 (v 128..255, 32K) ----
#pragma unroll
    for (int i = 0; i < 8; i++) {
        const int o = (wid * 8 + i) * 1024;
        __builtin_amdgcn_global_load_lds((gp_t)(gv + 32768 + o + lane * 16), (lp_t)(base + o), 16, 0, 0);
    }
    __syncthreads();   // b7: V1 ready

    // ==== PV chunk1: ni 8..15 (v 128..255; buf row = v-128) ====
    __builtin_amdgcn_s_setprio(1);
#pragma unroll
    for (int ks = 0; ks < 4; ks++) {
        const int pbyte = POFF + arow * 256 + ((ks * 64 + lq * 16) ^ aswz);
        bf16x8 pa = *(const bf16x8*)(base + pbyte);
#pragma unroll
        for (int ni = 8; ni < 16; ni++) {
            const int vrow = (ni - 8) * 16 + l16;
            const int vbyte = vrow * 256 + ((ks * 64 + lq * 16) ^ ((vrow & 7) << 4));
            bf16x8 bvv = *(const bf16x8*)(base + vbyte);
            acc2[ni] = __builtin_amdgcn_mfma_f32_16x16x32_bf16(pa, bvv, acc2[ni], 0, 0, 0);
        }
    }
    __builtin_amdgcn_s_setprio(0);
    __syncthreads();   // b8: buf free (V1 dead, P dead)

    // ---- write normalized ctx bf16 [64px][256v] swizzled into buf (32K exactly) ----
#pragma unroll
    for (int ni = 0; ni < 16; ni++) {
#pragma unroll
        for (int r = 0; r < 4; r++) {
            const int row = prow + r;
            const int v = ni * 16 + l16;
            const int byte = row * 512 + ((v * 2) ^ ((row & 7) << 4));
            *(u16*)(base + byte) = (u16)f2bf1(acc2[ni][r] * rn[r]);
        }
    }
    __syncthreads();   // b9: ctx ready

    // ==== fused out-GEMM in 2 c-halves of 64 (VGPR cap for 3 waves/SIMD) ====
    const int wc0 = wid * 128;
    float* outb = out + (size_t)b * CIN * HW + nblk;
    char* scr = base + POFF + wid * 4096;   // 4 KB/wave transpose scratch (P region, dead)

#pragma unroll
    for (int ch = 0; ch < 2; ch++) {
        f32x4 accg[4][4];   // [pi: px-tile][cj: c-tile of 16]
#pragma unroll
        for (int pi = 0; pi < 4; pi++)
#pragma unroll
            for (int cj = 0; cj < 4; cj++)
                accg[pi][cj] = (f32x4){0.f, 0.f, 0.f, 0.f};

        const u16* wwbase = Wwb + (size_t)(wc0 + ch * 64 + l16) * VC + lq * 8;
        __builtin_amdgcn_s_setprio(1);
#pragma unroll
        for (int ks = 0; ks < 8; ks++) {
            bf16x8 af[4];
#pragma unroll
            for (int pi = 0; pi < 4; pi++) {
                const int px = pi * 16 + l16;
                const int byte = px * 512 + ((ks * 64 + lq * 16) ^ ((px & 7) << 4));
                af[pi] = *(const bf16x8*)(base + byte);
            }
            bf16x8 bfr[4];
#pragma unroll
            for (int cj = 0; cj < 4; cj++)
                bfr[cj] = *(const bf16x8*)(wwbase + (size_t)cj * 16 * VC + ks * 32);
#pragma unroll
            for (int pi = 0; pi < 4; pi++)
#pragma unroll
                for (int cj = 0; cj < 4; cj++)
                    accg[pi][cj] = __builtin_amdgcn_mfma_f32_16x16x32_bf16(
                        af[pi], bfr[cj], accg[pi][cj], 0, 0, 0);
        }
        __builtin_amdgcn_s_setprio(0);

        // epilogue for these 64 c: per cj-tile of 16, wave-private LDS transpose
#pragma unroll
        for (int cj = 0; cj < 4; cj++) {
            const int cl = l16;                 // c-local row 0..15
            const int swz = (cl & 7) << 5;
#pragma unroll
            for (int pi = 0; pi < 4; pi++)
#pragma unroll
                for (int r = 0; r < 4; r++) {
                    const int px = pi * 16 + 4 * lq + r;
                    *(float*)(scr + cl * 256 + ((px * 4) ^ swz)) = accg[pi][cj][r];
                }
#pragma unroll
            for (int cr = 0; cr < 4; cr++) {
                const int cl2 = cr * 4 + lq;
                const int swz2 = (cl2 & 7) << 5;
                float4 vv = *(const float4*)(scr + cl2 * 256 + ((l16 * 16) ^ swz2));
                const int c = wc0 + ch * 64 + cj * 16 + cl2;
                const float bb = bw[c];
                vv.x += bb; vv.y += bb; vv.z += bb; vv.w += bb;
                *(float4*)&outb[(size_t)c * HW + l16 * 4] = vv;
            }
        }
    }
}

extern "C" void kernel_launch(void* const* d_in, const int* in_sizes, int n_in,
                              void* d_out, int out_size, void* d_ws, size_t ws_size,
                              hipStream_t stream)
{
    const float* x     = (const float*)d_in[0];
    const float* Wk    = (const float*)d_in[1];
    const float* bk    = (const float*)d_in[2];
    const float* gamma = (const float*)d_in[3];
    const float* beta  = (const float*)d_in[4];
    const float* rmean = (const float*)d_in[5];
    const float* rvar  = (const float*)d_in[6];
    const float* Wv    = (const float*)d_in[7];
    const float* bv    = (const float*)d_in[8];
    const float* Ww    = (const float*)d_in[9];
    const float* bw    = (const float*)d_in[10];
    float* out = (float*)d_out;

    float* ws    = (float*)d_ws;
    float* rpk   = ws;                                        // [8][72][15][256] f32
    u16*   xT    = (u16*)(rpk + (size_t)BATCH * 72 * 15 * KC); // [8][5184][512] bf16
    u16*   kT    = xT + (size_t)BATCH * HW * CIN;             // [8][5184][256] bf16
    u16*   pxb   = kT + (size_t)BATCH * HW * KC;              // [8][128][512] bf16
    u16*   keytb = pxb + (size_t)BATCH * SPV * CIN;           // [8][112][256] bf16 (swizzled)
    u16*   valT  = keytb + (size_t)BATCH * NSP * KC;          // [8][256][128] bf16 (swizzled)
    u16*   Wkbf  = valT + (size_t)BATCH * VC * SPV;           // [256][512] bf16
    u16*   Wwbf  = Wkbf + (size_t)KC * CIN;                   // [512][256] bf16
    u16*   Wvbf  = Wwbf + (size_t)CIN * VC;                   // [256][512] bf16
    float* inv   = (float*)(Wvbf + (size_t)KC * CIN);         // [256]
    float* bc    = inv + 256;                                 // [256]

    prep_kernel<<<1, 256, 0, stream>>>(bk, gamma, beta, rmean, rvar, inv, bc);
    cvt_w_kernel<<<384, 256, 0, stream>>>(Wk, Ww, Wv, Wkbf, Wwbf, Wvbf);
    psp_pool_px_kernel<<<dim3(CIN, BATCH), 128, 0, stream>>>(x, pxb);
    transpose_cvt_kernel<<<dim3(HW / 64, CIN / 64, BATCH), 256, 0, stream>>>(x, xT, CIN);
    // k = relu(BN(Wk @ x)) : bf16 kT only (pooling runs off kT)
    {
        const int nbx = (HW + 127) / 128, nby = KC / 128;
        gemm_nt_bf16<<<nbx * nby * BATCH, 256, 0, stream>>>(
            Wkbf, xT, nullptr, kT, KC, HW, CIN, nbx, nby, inv, bc, 1);
    }
    rowpool_k_kernel<<<dim3(72, BATCH), 256, 0, stream>>>(kT, rpk);
    binpool_k_kernel<<<dim3(NSP, BATCH), 256, 0, stream>>>(rpk, keytb);
    value_mfma_kernel<<<dim3(2, BATCH), 256, 0, stream>>>(Wvbf, pxb, bv, valT);
    // attention + fused out-GEMM (writes final output directly)
    attn_mfma_kernel<<<dim3(HW / 64, BATCH), 256, 0, stream>>>(
        kT, keytb, valT, Wwbf, bw, out);
}

// Round 17
// 155.375 us; speedup vs baseline: 1.0356x; 1.0154x over previous
//
#include <hip/hip_runtime.h>
#include <hip/hip_bf16.h>

#define HW    5184
#define WIDTH 72
#define CIN   512
#define KC    256
#define VC    256
#define NS    110
#define NSP   112   // padded s for QK^T (7*16)
#define SPV   128   // padded s for PV k-dim (4*32)
#define BATCH 8

typedef unsigned short u16;
typedef unsigned int   u32;
typedef __attribute__((ext_vector_type(8))) short bf16x8;   // 8 bf16 = 4 VGPRs
typedef __attribute__((ext_vector_type(4))) float f32x4;

typedef const __attribute__((address_space(1))) u32* gp_t;
typedef __attribute__((address_space(3))) u32* lp_t;

__device__ __forceinline__ u32 f2bf1(float f) {
    u32 u = __float_as_uint(f);
    return (u + 0x7FFFu + ((u >> 16) & 1u)) >> 16;   // RNE
}
__device__ __forceinline__ u32 pack2(float a, float b) {
    return f2bf1(a) | (f2bf1(b) << 16);
}
__device__ __forceinline__ float bf2f(u16 h) {
    return __uint_as_float((u32)h << 16);
}

// ---------------- cvt Wk/Ww/Wv fp32->bf16 (+ folded BN prep in block 0) ----------------
__global__ __launch_bounds__(256) void cvt_w_kernel(
    const float* __restrict__ Wk, const float* __restrict__ Ww, const float* __restrict__ Wv,
    u16* __restrict__ Wkbf, u16* __restrict__ Wwbf, u16* __restrict__ Wvbf,
    const float* __restrict__ bk, const float* __restrict__ gamma,
    const float* __restrict__ beta, const float* __restrict__ rmean,
    const float* __restrict__ rvar, float* __restrict__ inv_out, float* __restrict__ bc_out)
{
    int j = (blockIdx.x * 256 + threadIdx.x) * 4;   // grid 384 -> 393216 elems
    const float* s; u16* d;
    if (j < KC * CIN)          { s = Wk; d = Wkbf; }
    else if (j < 2 * KC * CIN) { j -= KC * CIN;     s = Ww; d = Wwbf; }
    else                       { j -= 2 * KC * CIN; s = Wv; d = Wvbf; }
    float4 v = *(const float4*)&s[j];
    uint2 u;
    u.x = pack2(v.x, v.y);
    u.y = pack2(v.z, v.w);
    *(uint2*)&d[j] = u;
    if (blockIdx.x == 0) {   // folded BN prep: one thread per Kc channel
        const int i = threadIdx.x;
        float inv = gamma[i] * rsqrtf(rvar[i] + 1e-5f);
        inv_out[i] = inv;
        bc_out[i]  = bk[i] * inv + beta[i] - rmean[i] * inv;
    }
}

// ---------------- transpose+cvt 64x64: in [z][C][5184] f32 -> out [z][5184][C] bf16 ----------------
__global__ __launch_bounds__(256) void transpose_cvt_kernel(
    const float* __restrict__ in, u16* __restrict__ out, int C)
{
    const int z  = blockIdx.z;
    const int n0 = blockIdx.x * 64;   // HW
    const int k0 = blockIdx.y * 64;   // C
    __shared__ float t[64][65];
    const int tx = threadIdx.x & 63, ty = threadIdx.x >> 6;   // ty 0..3
    const float* src = in + ((size_t)z * C + k0) * HW + n0;
#pragma unroll
    for (int i = 0; i < 16; i++)
        t[ty + i * 4][tx] = src[(size_t)(ty + i * 4) * HW + tx];   // 256B segments
    __syncthreads();
    u16* dst = out + ((size_t)z * HW + n0) * C + k0;
    const int kp  = (threadIdx.x & 31) * 2;
    const int nl0 = threadIdx.x >> 5;           // 0..7
#pragma unroll
    for (int j = 0; j < 8; j++) {
        int nl = nl0 + j * 8;
        u32 u = pack2(t[kp][nl], t[kp + 1][nl]);
        *(u32*)&dst[(size_t)nl * C + kp] = u;   // 128B segments
    }
}

// ---------------- bf16 MFMA NT-GEMM, counted-vmcnt 3-buffer pipeline ----------------
__global__ __launch_bounds__(256) void gemm_nt_bf16(
    const u16* __restrict__ A, const u16* __restrict__ B, float* __restrict__ C,
    u16* __restrict__ Ct,
    int M, int N, int K, int nbx, int nby,
    const float* __restrict__ scale, const float* __restrict__ bias, int relu)
{
    const int tot = nbx * nby * BATCH;
    const int q = tot >> 3, r = tot & 7;
    const int xcd = blockIdx.x & 7;
    const int wg  = (xcd < r ? xcd * (q + 1) : r * (q + 1) + (xcd - r) * q) + (blockIdx.x >> 3);
    const int mb_ = wg % nby;
    const int nb_ = (wg / nby) % nbx;
    const int z   = wg / (nby * nbx);

    const int n0 = nb_ * 128;
    const int m0 = mb_ * 128;
    const size_t boff = (size_t)z * N * K;
    const size_t coff = (size_t)z * M * N;
    const int tid  = threadIdx.x;
    const int wid  = tid >> 6;
    const int lane = tid & 63;

    __shared__ __align__(16) u16 As[3][4][128][8];
    __shared__ __align__(16) u16 Bs[3][4][128][8];

    const int kg0  = (wid & 1) * 2;
    const int half = (wid >> 1) * 64;

    const u16* gA = A + (size_t)(m0 + half + lane) * K + kg0 * 8;
    int nIdx = n0 + half + lane;
    if (nIdx > N - 1) nIdx = N - 1;
    const u16* gB = B + boff + (size_t)nIdx * K + kg0 * 8;

    const int wm  = (wid >> 1) * 64;
    const int wn  = (wid & 1) * 64;
    const int l16 = lane & 15;
    const int lq  = lane >> 4;

    f32x4 acc[4][4];
#pragma unroll
    for (int mi = 0; mi < 4; mi++)
#pragma unroll
        for (int ni = 0; ni < 4; ni++)
            acc[mi][ni] = (f32x4){0.f, 0.f, 0.f, 0.f};

#define STAGE(d, kk)                                                                              \
    __builtin_amdgcn_global_load_lds((gp_t)(gA + (kk)),     (lp_t)&As[d][kg0][half][0], 16, 0, 0);\
    __builtin_amdgcn_global_load_lds((gp_t)(gA + (kk) + 8), (lp_t)&As[d][kg0+1][half][0],16, 0, 0);\
    __builtin_amdgcn_global_load_lds((gp_t)(gB + (kk)),     (lp_t)&Bs[d][kg0][half][0], 16, 0, 0);\
    __builtin_amdgcn_global_load_lds((gp_t)(gB + (kk) + 8), (lp_t)&Bs[d][kg0+1][half][0],16, 0, 0);

    const int NT = K >> 5;
    STAGE(0, 0)
    STAGE(1, 32)

    int cur = 0;
    for (int t = 0; t < NT; ++t) {
        if (t + 1 < NT) { asm volatile("s_waitcnt vmcnt(4)" ::: "memory"); }
        else            { asm volatile("s_waitcnt vmcnt(0)" ::: "memory"); }
        __builtin_amdgcn_s_barrier();
        __builtin_amdgcn_sched_barrier(0);

        if (t + 2 < NT) {
            int nb = cur + 2; if (nb >= 3) nb -= 3;
            STAGE(nb, (t + 2) * 32)
        }

        bf16x8 af[4], bf[4];
#pragma unroll
        for (int i = 0; i < 4; i++) {
            af[i] = *(const bf16x8*)&As[cur][lq][wm + i * 16 + l16][0];
            bf[i] = *(const bf16x8*)&Bs[cur][lq][wn + i * 16 + l16][0];
        }
        __builtin_amdgcn_s_setprio(1);
#pragma unroll
        for (int mi = 0; mi < 4; mi++)
#pragma unroll
            for (int ni = 0; ni < 4; ni++)
                acc[mi][ni] = __builtin_amdgcn_mfma_f32_16x16x32_bf16(
                    af[mi], bf[ni], acc[mi][ni], 0, 0, 0);
        __builtin_amdgcn_s_setprio(0);

        cur = (cur == 2) ? 0 : cur + 1;
    }
#undef STAGE

#pragma unroll
    for (int mi = 0; mi < 4; mi++) {
        const int mb = m0 + wm + mi * 16 + lq * 4;
        float sc[4], bi[4];
#pragma unroll
        for (int r2 = 0; r2 < 4; r2++) {
            sc[r2] = scale ? scale[mb + r2] : 1.0f;
            bi[r2] = bias  ? bias[mb + r2]  : 0.0f;
        }
#pragma unroll
        for (int ni = 0; ni < 4; ni++) {
            const int n = n0 + wn + ni * 16 + l16;
            if (n < N) {
                float v[4];
#pragma unroll
                for (int r2 = 0; r2 < 4; r2++) {
                    v[r2] = acc[mi][ni][r2] * sc[r2] + bi[r2];
                    if (relu) v[r2] = fmaxf(v[r2], 0.f);
                }
                if (C) {
#pragma unroll
                    for (int r2 = 0; r2 < 4; r2++)
                        C[coff + (size_t)(mb + r2) * N + n] = v[r2];
                }
                if (Ct) {
                    uint2 u;
                    u.x = pack2(v[0], v[1]);
                    u.y = pack2(v[2], v[3]);
                    *(uint2*)&Ct[(size_t)z * N * M + (size_t)n * M + mb] = u;
                }
            }
        }
    }
}

// ---------------- row pooling over kT: [b][5184][256] bf16 -> rp [b][72][15][256] f32 ----------------
__global__ __launch_bounds__(256) void rowpool_k_kernel(
    const u16* __restrict__ kT, float* __restrict__ rp)
{
    const int y = blockIdx.x;
    const int b = blockIdx.y;
    const int c = threadIdx.x;
    const u16* src = kT + ((size_t)b * HW + (size_t)y * WIDTH) * KC + c;
    float s9[8]  = {0.f, 0.f, 0.f, 0.f, 0.f, 0.f, 0.f, 0.f};
    float s12[6] = {0.f, 0.f, 0.f, 0.f, 0.f, 0.f};
#pragma unroll
    for (int x = 0; x < 72; x++) {
        float v = bf2f(src[(size_t)x * KC]);
        s9[x / 9] += v;
        s12[x / 12] += v;
    }
    float* dst = rp + (((size_t)b * 72 + y) * 15) * KC + c;
    float tot = 0.f;
#pragma unroll
    for (int g = 0; g < 8; g++) dst[(size_t)g * KC] = s9[g];
#pragma unroll
    for (int g = 0; g < 6; g++) { dst[(size_t)(8 + g) * KC] = s12[g]; tot += s12[g]; }
    dst[(size_t)14 * KC] = tot;
}

// ---------------- bin pooling: rp -> keytb [b][112][256] bf16 SWIZZLED ----------------
__global__ __launch_bounds__(256) void binpool_k_kernel(
    const float* __restrict__ rp, u16* __restrict__ keytb)
{
    const int s = blockIdx.x;
    const int b = blockIdx.y;
    const int c = threadIdx.x;
    char* ob = (char*)keytb + (size_t)b * NSP * KC * 2;
    float sum = 0.f, scl = 0.f;
    const float* rpb = rp + (size_t)b * 72 * 15 * KC + c;
    if (s < NS) {
        if (s == 0) {
#pragma unroll 8
            for (int y = 0; y < 72; y++) sum += rpb[((size_t)y * 15 + 14) * KC];
            scl = 1.f / 5184.f;
        } else if (s < 10) {
            const int t = s - 1, gy = t / 3, gx = t - gy * 3;
#pragma unroll 8
            for (int i = 0; i < 24; i++) {
                const int y = gy * 24 + i;
                sum += rpb[((size_t)y * 15 + 8 + 2 * gx) * KC]
                     + rpb[((size_t)y * 15 + 9 + 2 * gx) * KC];
            }
            scl = 1.f / 576.f;
        } else if (s < 46) {
            const int t = s - 10, gy = t / 6, gx = t - gy * 6;
#pragma unroll
            for (int i = 0; i < 12; i++) {
                const int y = gy * 12 + i;
                sum += rpb[((size_t)y * 15 + 8 + gx) * KC];
            }
            scl = 1.f / 144.f;
        } else {
            const int t = s - 46, gy = t >> 3, gx = t & 7;
#pragma unroll
            for (int i = 0; i < 9; i++) {
                const int y = gy * 9 + i;
                sum += rpb[((size_t)y * 15 + gx) * KC];
            }
            scl = 1.f / 81.f;
        }
    }
    const int byte = s * 512 + ((c * 2) ^ ((s & 7) << 4));
    *(u16*)(ob + byte) = (s < NS) ? (u16)f2bf1(sum * scl) : (u16)0;
}

// ---------------- value MFMA GEMM: valT SWIZZLED [b][v][s] bf16 ----------------
__global__ __launch_bounds__(256) void value_mfma_kernel(
    const u16* __restrict__ A, const u16* __restrict__ Bp,
    const float* __restrict__ bv, u16* __restrict__ valT)
{
    const int m0 = blockIdx.x * 128;
    const int b  = blockIdx.y;
    const int tid  = threadIdx.x;
    const int wid  = tid >> 6;
    const int lane = tid & 63;

    __shared__ __align__(16) u16 As[4][128][8];
    __shared__ __align__(16) u16 Bs[4][128][8];

    const int kg0  = (wid & 1) * 2;
    const int half = (wid >> 1) * 64;

    const u16* gA = A + (size_t)(m0 + half + lane) * CIN + kg0 * 8;
    const u16* gB = Bp + (size_t)b * SPV * CIN + (size_t)(half + lane) * CIN + kg0 * 8;

    lp_t lA0 = (lp_t)&As[kg0][half][0];
    lp_t lA1 = (lp_t)&As[kg0 + 1][half][0];
    lp_t lB0 = (lp_t)&Bs[kg0][half][0];
    lp_t lB1 = (lp_t)&Bs[kg0 + 1][half][0];

    const int wm  = (wid >> 1) * 64;
    const int wn  = (wid & 1) * 64;
    const int l16 = lane & 15;
    const int lq  = lane >> 4;

    f32x4 acc[4][4];
#pragma unroll
    for (int mi = 0; mi < 4; mi++)
#pragma unroll
        for (int ni = 0; ni < 4; ni++)
            acc[mi][ni] = (f32x4){0.f, 0.f, 0.f, 0.f};

    for (int k0 = 0; k0 < CIN; k0 += 32) {
        __builtin_amdgcn_global_load_lds((gp_t)(gA + k0),     lA0, 16, 0, 0);
        __builtin_amdgcn_global_load_lds((gp_t)(gA + k0 + 8), lA1, 16, 0, 0);
        __builtin_amdgcn_global_load_lds((gp_t)(gB + k0),     lB0, 16, 0, 0);
        __builtin_amdgcn_global_load_lds((gp_t)(gB + k0 + 8), lB1, 16, 0, 0);
        __syncthreads();

        bf16x8 af[4], bf[4];
#pragma unroll
        for (int i = 0; i < 4; i++) {
            af[i] = *(const bf16x8*)&As[lq][wm + i * 16 + l16][0];
            bf[i] = *(const bf16x8*)&Bs[lq][wn + i * 16 + l16][0];
        }
#pragma unroll
        for (int mi = 0; mi < 4; mi++)
#pragma unroll
            for (int ni = 0; ni < 4; ni++)
                acc[mi][ni] = __builtin_amdgcn_mfma_f32_16x16x32_bf16(
                    af[mi], bf[ni], acc[mi][ni], 0, 0, 0);
        __syncthreads();
    }

    char* vb = (char*)valT + (size_t)b * VC * SPV * 2;
#pragma unroll
    for (int mi = 0; mi < 4; mi++) {
        const int mb = m0 + wm + mi * 16 + lq * 4;
        float bi[4];
#pragma unroll
        for (int r = 0; r < 4; r++) bi[r] = bv[mb + r];
#pragma unroll
        for (int ni = 0; ni < 4; ni++) {
            const int n = wn + ni * 16 + l16;
#pragma unroll
            for (int r = 0; r < 4; r++) {
                const int v = mb + r;
                const int byte = v * 256 + ((n * 2) ^ ((v & 7) << 4));
                *(u16*)(vb + byte) = (u16)f2bf1(acc[mi][ni][r] + bi[r]);
            }
        }
    }
}

// ---------------- PSP pooling px: x [b][512][5184] f32 -> pxb [b][128][512] bf16 ----------------
__global__ __launch_bounds__(128) void psp_pool_px_kernel(
    const float* __restrict__ in, u16* __restrict__ out)
{
    const int c = blockIdx.x;   // 0..511
    const int b = blockIdx.y;
    const int t = threadIdx.x;
    __shared__ float4 row4[1296];
    __shared__ float aux[100];
    float* row = (float*)row4;
    const float* src = in + ((size_t)b * CIN + c) * HW;
    for (int idx = t; idx < 1296; idx += 128)
        row4[idx] = *(const float4*)(src + idx * 4);
    __syncthreads();
    if (t < 64) {
        int r0 = (t >> 3) * 9, c0 = (t & 7) * 9;
        float s = 0.f;
        for (int i = 0; i < 9; i++)
            for (int j = 0; j < 9; j++) s += row[(r0 + i) * WIDTH + c0 + j];
        aux[t] = s;
    } else if (t < 100) {
        int tt = t - 64;
        int r0 = (tt / 6) * 12, c0 = (tt % 6) * 12;
        float s = 0.f;
        for (int i = 0; i < 12; i++)
            for (int j = 0; j < 12; j++) s += row[(r0 + i) * WIDTH + c0 + j];
        aux[64 + tt] = s;
    }
    __syncthreads();
    u16* ob = out + (size_t)b * SPV * CIN + c;
    if (t < 64) ob[(size_t)(46 + t) * CIN] = (u16)f2bf1(aux[t] * (1.f / 81.f));
    if (t < 36) ob[(size_t)(10 + t) * CIN] = (u16)f2bf1(aux[64 + t] * (1.f / 144.f));
    if (t < 9) {
        int r = t / 3, cc = t % 3;
        float s4 = aux[64 + (2 * r) * 6 + 2 * cc] + aux[64 + (2 * r) * 6 + 2 * cc + 1]
                 + aux[64 + (2 * r + 1) * 6 + 2 * cc] + aux[64 + (2 * r + 1) * 6 + 2 * cc + 1];
        ob[(size_t)(1 + t) * CIN] = (u16)f2bf1(s4 * (1.f / 576.f));
    }
    if (t == 0) {
        float s = 0.f;
        for (int i = 0; i < 64; i++) s += aux[i];
        ob[0] = (u16)f2bf1(s * (1.f / 5184.f));
    }
    if (t < 18) ob[(size_t)(110 + t) * CIN] = 0;   // zero pad rows
}

// ---------------- MFMA attention + FUSED output GEMM, 48 KB LDS (3 blocks/CU) ----------------
// One 32K buffer time-multiplexed: K0(s0-63) -> K1(s64-111) -> V0(v0-127) -> V1(v128-255) -> ctx.
// P 16K at [32K,48K), doubles as 4KB/wave transpose scratch in epilogue.
// s_setprio(1) wrapped around all MFMA clusters (T5: phase-split schedule).
__global__ __launch_bounds__(256, 3) void attn_mfma_kernel(
    const u16* __restrict__ qT, const u16* __restrict__ keyt,
    const u16* __restrict__ valT, const u16* __restrict__ Wwb,
    const float* __restrict__ bw, float* __restrict__ out)
{
    const int b    = blockIdx.y;
    const int tid  = threadIdx.x;
    const int wid  = tid >> 6;
    const int lane = tid & 63;
    const int l16  = lane & 15;
    const int lq   = lane >> 4;
    const int nblk = blockIdx.x * 64;              // block's 64-px base
    const int px0  = nblk + wid * 16;              // wave's 16-px row base

    __shared__ __align__(16) u16 SM[24576];        // 48 KiB -> 3 blocks/CU
    char* base = (char*)SM;
    const int POFF = 32768;                        // P region [32K,48K)

    const char* gk = (const char*)keyt + (size_t)b * (NSP * KC * 2);
    const char* gv = (const char*)valT + (size_t)b * (VC * SPV * 2);

    // ---- stage K0 (s 0..63, 32K) ----
#pragma unroll
    for (int i = 0; i < 8; i++) {
        const int o = (wid * 8 + i) * 1024;
        __builtin_amdgcn_global_load_lds((gp_t)(gk + o + lane * 16), (lp_t)(base + o), 16, 0, 0);
    }

    // ---- preload all 8 q fragments (overlaps with staging drain) ----
    const u16* qrow = qT + ((size_t)b * HW + px0 + l16) * KC + lq * 8;
    bf16x8 aq[8];
#pragma unroll
    for (int ks = 0; ks < 8; ks++) aq[ks] = *(const bf16x8*)(qrow + ks * 32);

    __syncthreads();   // b1: K0 ready

    // ==== QK^T chunk0: ni 0..3 (s 0..63) ====
    f32x4 acc[7];
#pragma unroll
    for (int ni = 0; ni < 7; ni++) acc[ni] = (f32x4){0.f, 0.f, 0.f, 0.f};
    __builtin_amdgcn_s_setprio(1);
#pragma unroll
    for (int ks = 0; ks < 8; ks++) {
#pragma unroll
        for (int ni = 0; ni < 4; ni++) {
            const int s = ni * 16 + l16;
            const int byte = s * 512 + ((ks * 64 + lq * 16) ^ ((s & 7) << 4));
            bf16x8 bk = *(const bf16x8*)(base + byte);
            acc[ni] = __builtin_amdgcn_mfma_f32_16x16x32_bf16(aq[ks], bk, acc[ni], 0, 0, 0);
        }
    }
    __builtin_amdgcn_s_setprio(0);
    __syncthreads();   // b2: K0 dead

    // ---- stage K1 (s 64..111, 24K) ----
#pragma unroll
    for (int i = 0; i < 6; i++) {
        const int o = (wid * 6 + i) * 1024;
        __builtin_amdgcn_global_load_lds((gp_t)(gk + 32768 + o + lane * 16), (lp_t)(base + o), 16, 0, 0);
    }
    __syncthreads();   // b3: K1 ready

    // ==== QK^T chunk1: ni 4..6 (s 64..111; buf row = s-64) ====
    __builtin_amdgcn_s_setprio(1);
#pragma unroll
    for (int ks = 0; ks < 8; ks++) {
#pragma unroll
        for (int ni = 4; ni < 7; ni++) {
            const int s = ni * 16 + l16;
            const int srow = s - 64;
            const int byte = srow * 512 + ((ks * 64 + lq * 16) ^ ((srow & 7) << 4));
            bf16x8 bk = *(const bf16x8*)(base + byte);
            acc[ni] = __builtin_amdgcn_mfma_f32_16x16x32_bf16(aq[ks], bk, acc[ni], 0, 0, 0);
        }
    }
    __builtin_amdgcn_s_setprio(0);
    if (l16 >= 14) acc[6] = (f32x4){-1e30f, -1e30f, -1e30f, -1e30f};  // mask s=110,111
    __syncthreads();   // b4: K1 dead -> buf free for V0

    // ---- stage V0 (v 0..127, 32K) -- latency hides under softmax below ----
#pragma unroll
    for (int i = 0; i < 8; i++) {
        const int o = (wid * 8 + i) * 1024;
        __builtin_amdgcn_global_load_lds((gp_t)(gv + o + lane * 16), (lp_t)(base + o), 16, 0, 0);
    }

    // ==== softmax (in-register), P writes to own region ====
    float mx[4], sm[4], rn[4];
#pragma unroll
    for (int r = 0; r < 4; r++) {
        float m = acc[0][r];
#pragma unroll
        for (int ni = 1; ni < 7; ni++) m = fmaxf(m, acc[ni][r]);
        m = fmaxf(m, __shfl_xor(m, 1));
        m = fmaxf(m, __shfl_xor(m, 2));
        m = fmaxf(m, __shfl_xor(m, 4));
        m = fmaxf(m, __shfl_xor(m, 8));
        mx[r] = m * 0.0625f;
        sm[r] = 0.f;
    }

    const int prow = wid * 16 + 4 * lq;
#pragma unroll
    for (int ni = 0; ni < 7; ni++) {
#pragma unroll
        for (int r = 0; r < 4; r++) {
            float p = __expf(acc[ni][r] * 0.0625f - mx[r]);
            sm[r] += p;
            const int row = prow + r;
            const int byte = POFF + row * 256 + (((ni * 16 + l16) * 2) ^ ((row & 7) << 4));
            *(u16*)(base + byte) = (u16)f2bf1(p);
        }
    }
    if (l16 < 2) {   // zero pad cols 112..127
#pragma unroll
        for (int r = 0; r < 4; r++) {
            const int row = prow + r;
            const int byte = POFF + row * 256 + ((224 + l16 * 16) ^ ((row & 7) << 4));
            *(bf16x8*)(base + byte) = (bf16x8){0, 0, 0, 0, 0, 0, 0, 0};
        }
    }
#pragma unroll
    for (int r = 0; r < 4; r++) {
        float s = sm[r];
        s += __shfl_xor(s, 1);
        s += __shfl_xor(s, 2);
        s += __shfl_xor(s, 4);
        s += __shfl_xor(s, 8);
        rn[r] = 1.f / s;
    }
    __syncthreads();   // b5: V0 ready (vmcnt drained), P visible

    // ==== PV chunk0: ni 0..7 (v 0..127) ====
    f32x4 acc2[16];
#pragma unroll
    for (int ni = 0; ni < 16; ni++) acc2[ni] = (f32x4){0.f, 0.f, 0.f, 0.f};
    const int arow = wid * 16 + l16;
    const int aswz = (arow & 7) << 4;
    __builtin_amdgcn_s_setprio(1);
#pragma unroll
    for (int ks = 0; ks < 4; ks++) {
        const int pbyte = POFF + arow * 256 + ((ks * 64 + lq * 16) ^ aswz);
        bf16x8 pa = *(const bf16x8*)(base + pbyte);
#pragma unroll
        for (int ni = 0; ni < 8; ni++) {
            const int v = ni * 16 + l16;
            const int vbyte = v * 256 + ((ks * 64 + lq * 16) ^ ((v & 7) << 4));
            bf16x8 bvv = *(const bf16x8*)(base + vbyte);
            acc2[ni] = __builtin_amdgcn_mfma_f32_16x16x32_bf16(pa, bvv, acc2[ni], 0, 0, 0);
        }
    }
    __builtin_amdgcn_s_setprio(0);
    __syncthreads();   // b6: V0 dead

    // ---- stage V1 (v 128..255, 32K) ----
#pragma unroll
    for (int i = 0; i < 8; i++) {
        const int o = (wid * 8 + i) * 1024;
        __builtin_amdgcn_global_load_lds((gp_t)(gv + 32768 + o + lane * 16), (lp_t)(base + o), 16, 0, 0);
    }
    __syncthreads();   // b7: V1 ready

    // ==== PV chunk1: ni 8..15 (v 128..255; buf row = v-128) ====
    __builtin_amdgcn_s_setprio(1);
#pragma unroll
    for (int ks = 0; ks < 4; ks++) {
        const int pbyte = POFF + arow * 256 + ((ks * 64 + lq * 16) ^ aswz);
        bf16x8 pa = *(const bf16x8*)(base + pbyte);
#pragma unroll
        for (int ni = 8; ni < 16; ni++) {
            const int vrow = (ni - 8) * 16 + l16;
            const int vbyte = vrow * 256 + ((ks * 64 + lq * 16) ^ ((vrow & 7) << 4));
            bf16x8 bvv = *(const bf16x8*)(base + vbyte);
            acc2[ni] = __builtin_amdgcn_mfma_f32_16x16x32_bf16(pa, bvv, acc2[ni], 0, 0, 0);
        }
    }
    __builtin_amdgcn_s_setprio(0);
    __syncthreads();   // b8: buf free (V1 dead, P dead)

    // ---- write normalized ctx bf16 [64px][256v] swizzled into buf (32K exactly) ----
#pragma unroll
    for (int ni = 0; ni < 16; ni++) {
#pragma unroll
        for (int r = 0; r < 4; r++) {
            const int row = prow + r;
            const int v = ni * 16 + l16;
            const int byte = row * 512 + ((v * 2) ^ ((row & 7) << 4));
            *(u16*)(base + byte) = (u16)f2bf1(acc2[ni][r] * rn[r]);
        }
    }
    __syncthreads();   // b9: ctx ready

    // ==== fused out-GEMM in 2 c-halves of 64 (VGPR cap for 3 waves/SIMD) ====
    const int wc0 = wid * 128;
    float* outb = out + (size_t)b * CIN * HW + nblk;
    char* scr = base + POFF + wid * 4096;   // 4 KB/wave transpose scratch (P region, dead)

#pragma unroll
    for (int ch = 0; ch < 2; ch++) {
        f32x4 accg[4][4];   // [pi: px-tile][cj: c-tile of 16]
#pragma unroll
        for (int pi = 0; pi < 4; pi++)
#pragma unroll
            for (int cj = 0; cj < 4; cj++)
                accg[pi][cj] = (f32x4){0.f, 0.f, 0.f, 0.f};

        const u16* wwbase = Wwb + (size_t)(wc0 + ch * 64 + l16) * VC + lq * 8;
        __builtin_amdgcn_s_setprio(1);
#pragma unroll
        for (int ks = 0; ks < 8; ks++) {
            bf16x8 af[4];
#pragma unroll
            for (int pi = 0; pi < 4; pi++) {
                const int px = pi * 16 + l16;
                const int byte = px * 512 + ((ks * 64 + lq * 16) ^ ((px & 7) << 4));
                af[pi] = *(const bf16x8*)(base + byte);
            }
            bf16x8 bfr[4];
#pragma unroll
            for (int cj = 0; cj < 4; cj++)
                bfr[cj] = *(const bf16x8*)(wwbase + (size_t)cj * 16 * VC + ks * 32);
#pragma unroll
            for (int pi = 0; pi < 4; pi++)
#pragma unroll
                for (int cj = 0; cj < 4; cj++)
                    accg[pi][cj] = __builtin_amdgcn_mfma_f32_16x16x32_bf16(
                        af[pi], bfr[cj], accg[pi][cj], 0, 0, 0);
        }
        __builtin_amdgcn_s_setprio(0);

        // epilogue for these 64 c: per cj-tile of 16, wave-private LDS transpose
#pragma unroll
        for (int cj = 0; cj < 4; cj++) {
            const int cl = l16;                 // c-local row 0..15
            const int swz = (cl & 7) << 5;
#pragma unroll
            for (int pi = 0; pi < 4; pi++)
#pragma unroll
                for (int r = 0; r < 4; r++) {
                    const int px = pi * 16 + 4 * lq + r;
                    *(float*)(scr + cl * 256 + ((px * 4) ^ swz)) = accg[pi][cj][r];
                }
#pragma unroll
            for (int cr = 0; cr < 4; cr++) {
                const int cl2 = cr * 4 + lq;
                const int swz2 = (cl2 & 7) << 5;
                float4 vv = *(const float4*)(scr + cl2 * 256 + ((l16 * 16) ^ swz2));
                const int c = wc0 + ch * 64 + cj * 16 + cl2;
                const float bb = bw[c];
                vv.x += bb; vv.y += bb; vv.z += bb; vv.w += bb;
                *(float4*)&outb[(size_t)c * HW + l16 * 4] = vv;
            }
        }
    }
}

extern "C" void kernel_launch(void* const* d_in, const int* in_sizes, int n_in,
                              void* d_out, int out_size, void* d_ws, size_t ws_size,
                              hipStream_t stream)
{
    const float* x     = (const float*)d_in[0];
    const float* Wk    = (const float*)d_in[1];
    const float* bk    = (const float*)d_in[2];
    const float* gamma = (const float*)d_in[3];
    const float* beta  = (const float*)d_in[4];
    const float* rmean = (const float*)d_in[5];
    const float* rvar  = (const float*)d_in[6];
    const float* Wv    = (const float*)d_in[7];
    const float* bv    = (const float*)d_in[8];
    const float* Ww    = (const float*)d_in[9];
    const float* bw    = (const float*)d_in[10];
    float* out = (float*)d_out;

    float* ws    = (float*)d_ws;
    float* rpk   = ws;                                        // [8][72][15][256] f32
    u16*   xT    = (u16*)(rpk + (size_t)BATCH * 72 * 15 * KC); // [8][5184][512] bf16
    u16*   kT    = xT + (size_t)BATCH * HW * CIN;             // [8][5184][256] bf16
    u16*   pxb   = kT + (size_t)BATCH * HW * KC;              // [8][128][512] bf16
    u16*   keytb = pxb + (size_t)BATCH * SPV * CIN;           // [8][112][256] bf16 (swizzled)
    u16*   valT  = keytb + (size_t)BATCH * NSP * KC;          // [8][256][128] bf16 (swizzled)
    u16*   Wkbf  = valT + (size_t)BATCH * VC * SPV;           // [256][512] bf16
    u16*   Wwbf  = Wkbf + (size_t)KC * CIN;                   // [512][256] bf16
    u16*   Wvbf  = Wwbf + (size_t)CIN * VC;                   // [256][512] bf16
    float* inv   = (float*)(Wvbf + (size_t)KC * CIN);         // [256]
    float* bc    = inv + 256;                                 // [256]

    cvt_w_kernel<<<384, 256, 0, stream>>>(Wk, Ww, Wv, Wkbf, Wwbf, Wvbf,
                                          bk, gamma, beta, rmean, rvar, inv, bc);
    psp_pool_px_kernel<<<dim3(CIN, BATCH), 128, 0, stream>>>(x, pxb);
    transpose_cvt_kernel<<<dim3(HW / 64, CIN / 64, BATCH), 256, 0, stream>>>(x, xT, CIN);
    // k = relu(BN(Wk @ x)) : bf16 kT only (pooling runs off kT)
    {
        const int nbx = (HW + 127) / 128, nby = KC / 128;
        gemm_nt_bf16<<<nbx * nby * BATCH, 256, 0, stream>>>(
            Wkbf, xT, nullptr, kT, KC, HW, CIN, nbx, nby, inv, bc, 1);
    }
    rowpool_k_kernel<<<dim3(72, BATCH), 256, 0, stream>>>(kT, rpk);
    binpool_k_kernel<<<dim3(NSP, BATCH), 256, 0, stream>>>(rpk, keytb);
    value_mfma_kernel<<<dim3(2, BATCH), 256, 0, stream>>>(Wvbf, pxb, bv, valT);
    // attention + fused out-GEMM (writes final output directly)
    attn_mfma_kernel<<<dim3(HW / 64, BATCH), 256, 0, stream>>>(
        kT, keytb, valT, Wwbf, bw, out);
}